// Round 1
// baseline (246.818 us; speedup 1.0000x reference)
//
#include <hip/hip_runtime.h>
#include <hip/hip_bf16.h>
#include <stdint.h>

// ---------------------------------------------------------------------------
// Self-attention, single head, d=1024, seq=2048, batch=4, fp32 in/out.
// R8: gemm_qkv + gemm_s_exp ported to the 256x256, BK=64, 8-wave, 8-phase
//     counted-vmcnt schedule (m201 template): raw s_barrier (no drain),
//     1 half-tile global_load_lds stage per phase, s_waitcnt vmcnt(4) only
//     at end of phases 4/8, setprio(1) around each 16-MFMA cluster.
//     LDS 128 KiB (2 bufs x [256x64] x A,B), 1 block/CU, 8 waves.
//     XOR chunk swizzle identical to R7 (lane i fetches K-chunk
//     (i&7)^(i>>3); reader chunk = ch ^ (row&7)) -> conflict-free b128 reads.
//     Staging safety (verified): B(t) read only in t's phase0 -> restage
//     slot +2 phases; A(t) read phases 0-3 -> A(t+1) staging deferred to
//     next iteration's phi0/phi1; both gates = vmcnt(4).
//     gemm_pv / cast_all unchanged from R7 (PV port next round).
// Pipeline: cast_all | QKV = xb @ wcat^T (Q/32, V->Vt scatter) |
//           S = exp(QK^T) + rowsum partials | O = (P Vt^T)/rowsum
// Workspace (102 MiB): xb @ 0 (16; 1st MiB reused as part after qkv)
//   wcat @ 16 (6)  Q @ 22 (16)  K @ 38 (16)  Vt @ 54 (16)  S @ 70 (32)
// ---------------------------------------------------------------------------

typedef __attribute__((ext_vector_type(8))) short bf16x8;   // 8 bf16 = 4 VGPRs
typedef __attribute__((ext_vector_type(4))) float f32x4;

__device__ __forceinline__ void async_copy16(const void* g, void* l) {
  __builtin_amdgcn_global_load_lds(
      (__attribute__((address_space(1))) void*)(g),
      (__attribute__((address_space(3))) void*)(l),
      16, 0, 0);
}

// ---- 256x256 / BK=64 / 8-phase double-buffered mainloop, K=1024 (NT=16) ----
// aS/bS: per-lane staging source = Op + (tile_base + srow)*1024 + scol
// As/Bs: LDS [2][256*64] bf16 (32768 B per buffer)
__device__ __forceinline__ void mainloop256(
    const __hip_bfloat16* __restrict__ aS,
    const __hip_bfloat16* __restrict__ bS,
    __hip_bfloat16* As, __hip_bfloat16* Bs,
    const int wid, const int wm, const int wn,
    const int l16, const int quad, const int sw,
    f32x4 (&acc)[8][4])
{
  const bf16x8* Av = (const bf16x8*)As;
  const bf16x8* Bv = (const bf16x8*)Bs;
  char* lA = (char*)As + wid * 1024;     // wave-uniform stage base
  char* lB = (char*)Bs + wid * 1024;
  bf16x8 bfr[4][2];                      // B frags, loaded in phase0, held 4 phases

#define STG_A(t, h) do { \
    async_copy16(aS + (((h)*128 +  0) * 1024 + (t)*64), lA + ((t)&1)*32768 + ((h)*128 +  0)*128); \
    async_copy16(aS + (((h)*128 + 64) * 1024 + (t)*64), lA + ((t)&1)*32768 + ((h)*128 + 64)*128); \
  } while (0)
#define STG_B(t, h) do { \
    async_copy16(bS + (((h)*128 +  0) * 1024 + (t)*64), lB + ((t)&1)*32768 + ((h)*128 +  0)*128); \
    async_copy16(bS + (((h)*128 + 64) * 1024 + (t)*64), lB + ((t)&1)*32768 + ((h)*128 + 64)*128); \
  } while (0)

  // one phase: ds-reads | stage issue | BAR | lgkmcnt(0) | 16 MFMA | tail | BAR
#define PH(t, phi, LOADB, STAGE_STMT, TAIL_STMT) do { \
    bf16x8 af[2][2]; \
    const int bofs = ((t)&1) * 2048;  /* buffer offset in bf16x8 units */ \
    _Pragma("unroll") \
    for (int m2 = 0; m2 < 2; ++m2) \
      _Pragma("unroll") \
      for (int kk = 0; kk < 2; ++kk) \
        af[m2][kk] = Av[bofs + (wm + ((phi)*2 + m2)*16 + l16)*8 + ((kk*4 + quad) ^ sw)]; \
    if (LOADB) { \
      _Pragma("unroll") \
      for (int ni = 0; ni < 4; ++ni) \
        _Pragma("unroll") \
        for (int kk = 0; kk < 2; ++kk) \
          bfr[ni][kk] = Bv[bofs + (wn + ni*16 + l16)*8 + ((kk*4 + quad) ^ sw)]; \
    } \
    STAGE_STMT; \
    __builtin_amdgcn_sched_barrier(0); \
    __builtin_amdgcn_s_barrier(); \
    asm volatile("s_waitcnt lgkmcnt(0)"); \
    __builtin_amdgcn_sched_barrier(0); \
    __builtin_amdgcn_s_setprio(1); \
    _Pragma("unroll") \
    for (int kk = 0; kk < 2; ++kk) \
      _Pragma("unroll") \
      for (int m2 = 0; m2 < 2; ++m2) \
        _Pragma("unroll") \
        for (int ni = 0; ni < 4; ++ni) \
          acc[(phi)*2 + m2][ni] = __builtin_amdgcn_mfma_f32_16x16x32_bf16( \
              af[m2][kk], bfr[ni][kk], acc[(phi)*2 + m2][ni], 0, 0, 0); \
    __builtin_amdgcn_s_setprio(0); \
    TAIL_STMT; \
    __builtin_amdgcn_sched_barrier(0); \
    __builtin_amdgcn_s_barrier(); \
  } while (0)

  // prologue: B(0), A(0), B(1); allow B(1)'s 4 loads outstanding
  STG_B(0, 0); STG_B(0, 1); STG_A(0, 0); STG_A(0, 1); STG_B(1, 0); STG_B(1, 1);
  asm volatile("s_waitcnt vmcnt(4)");
  __builtin_amdgcn_s_barrier();

  // steady state: iteration i computes tiles ta=2i (buf0), tb=2i+1 (buf1).
  // stage slots: ph0:A(tb)h0 ph1:A(tb)h1 ph2:B(ta+2)h0 ph3:B(ta+2)h1 [vmcnt4]
  //              ph4:A(ta+2)h0 ph5:A(ta+2)h1 ph6:B(tb+2)h0 ph7:B(tb+2)h1 [vmcnt4]
  #pragma unroll 1
  for (int i = 0; i < 7; ++i) {
    const int ta = 2 * i, tb = 2 * i + 1;
    PH(ta, 0, true,  STG_A(tb, 0),     (void)0);
    PH(ta, 1, false, STG_A(tb, 1),     (void)0);
    PH(ta, 2, false, STG_B(ta + 2, 0), (void)0);
    PH(ta, 3, false, STG_B(ta + 2, 1), asm volatile("s_waitcnt vmcnt(4)"));
    PH(tb, 0, true,  STG_A(ta + 2, 0), (void)0);
    PH(tb, 1, false, STG_A(ta + 2, 1), (void)0);
    PH(tb, 2, false, STG_B(tb + 2, 0), (void)0);
    PH(tb, 3, false, STG_B(tb + 2, 1), asm volatile("s_waitcnt vmcnt(4)"));
  }
  // peeled last iteration: tiles 14, 15 — only A(15) left to stage
  PH(14, 0, true,  STG_A(15, 0), (void)0);
  PH(14, 1, false, STG_A(15, 1), (void)0);
  PH(14, 2, false, (void)0,      (void)0);
  PH(14, 3, false, (void)0,      asm volatile("s_waitcnt vmcnt(0)"));
  PH(15, 0, true,  (void)0, (void)0);
  PH(15, 1, false, (void)0, (void)0);
  PH(15, 2, false, (void)0, (void)0);
  PH(15, 3, false, (void)0, (void)0);

#undef PH
#undef STG_A
#undef STG_B
}

// ---------------- fused QKV projection, 256x256 8-phase ----------------
// A = xb [8192,1024], B = wcat [3072,1024] (Wq | Wk | Wv rows)
// Q,K -> [8192,1024] bf16 (Q/32); V -> Vt [4][1024][2048] via 8B scatter.
__global__ __launch_bounds__(512, 2)
void gemm_qkv(const __hip_bfloat16* __restrict__ A,
              const __hip_bfloat16* __restrict__ B,
              __hip_bfloat16* __restrict__ Q,
              __hip_bfloat16* __restrict__ Kk,
              __hip_bfloat16* __restrict__ Vt)
{
  __shared__ __align__(16) __hip_bfloat16 As[2][256 * 64];   // 64 KB
  __shared__ __align__(16) __hip_bfloat16 Bs[2][256 * 64];   // 64 KB

  // XCD-chunked bijective swizzle: 384 blocks = 8 * 48; same-XCD blocks
  // share 4 consecutive tile_m panels (A reuse in per-XCD L2).
  const int bid = blockIdx.x;
  const int s   = (bid & 7) * 48 + (bid >> 3);
  const long long tile_m = (long long)(s / 12) * 256;
  const long long tile_n = (long long)(s % 12) * 256;

  const int tid  = threadIdx.x;
  const int wid  = tid >> 6;
  const int lane = tid & 63;
  const int srow = wid * 8 + (lane >> 3);
  const int scol = ((lane & 7) ^ (lane >> 3)) * 8;   // swizzled source chunk

  const __hip_bfloat16* aS = A + (tile_m + srow) * 1024 + scol;
  const __hip_bfloat16* bS = B + (tile_n + srow) * 1024 + scol;

  const int wm   = (wid >> 2) * 128;
  const int wn   = (wid & 3) * 64;
  const int quad = lane >> 4;
  const int l16  = lane & 15;
  const int sw   = l16 & 7;

  f32x4 acc[8][4];
  #pragma unroll
  for (int mi = 0; mi < 8; ++mi)
    #pragma unroll
    for (int ni = 0; ni < 4; ++ni)
      acc[mi][ni] = (f32x4){0.f, 0.f, 0.f, 0.f};

  mainloop256(aS, bS, &As[0][0], &Bs[0][0], wid, wm, wn, l16, quad, sw, acc);

  const int mat = (int)(tile_n >> 10);
  if (mat < 2) {
    // Q / K direct write.  C/D layout (m89/m91): col = l16, row = quad*4 + r
    __hip_bfloat16* outp = (mat == 0) ? Q : Kk;
    const float scale = (mat == 0) ? 0.03125f : 1.0f;   // 1/sqrt(1024) in Q
    const int coln0 = (int)(tile_n & 1023);
    #pragma unroll
    for (int mi = 0; mi < 8; ++mi) {
      #pragma unroll
      for (int r = 0; r < 4; ++r) {
        const long long row = tile_m + wm + mi * 16 + quad * 4 + r;
        #pragma unroll
        for (int ni = 0; ni < 4; ++ni) {
          const int col = coln0 + wn + ni * 16 + l16;
          outp[row * 1024 + col] = __float2bfloat16(acc[mi][ni][r] * scale);
        }
      }
    }
  } else {
    // V: lane's 4 r-values are seq-consecutive -> one 8B store per (mi,ni).
    const int b    = (int)(tile_m >> 11);
    const int seq0 = (int)(tile_m & 2047);
    const int d0   = (int)(tile_n - 2048);
    #pragma unroll
    for (int mi = 0; mi < 8; ++mi) {
      const int seq = seq0 + wm + mi * 16 + quad * 4;
      #pragma unroll
      for (int ni = 0; ni < 4; ++ni) {
        const int d = d0 + wn + ni * 16 + l16;
        union { ushort4 u; unsigned short sh[4]; } pk;
        #pragma unroll
        for (int r = 0; r < 4; ++r)
          pk.sh[r] = __bfloat16_as_ushort(__float2bfloat16(acc[mi][ni][r]));
        *(ushort4*)(Vt + ((long long)(b * 1024 + d)) * 2048 + seq) = pk.u;
      }
    }
  }
}

// ---------------- S = exp(Q K^T) + row-sum partials, 256x256 8-phase ----------------
__global__ __launch_bounds__(512, 2)
void gemm_s_exp(const __hip_bfloat16* __restrict__ A,
                const __hip_bfloat16* __restrict__ B,
                __hip_bfloat16* __restrict__ Cout,
                float* __restrict__ part)
{
  __shared__ __align__(16) __hip_bfloat16 As[2][256 * 64];   // 64 KB
  __shared__ __align__(16) __hip_bfloat16 Bs[2][256 * 64];   // 64 KB

  const int bz = blockIdx.z;
  A += (long long)bz * 2048 * 1024;
  B += (long long)bz * 2048 * 1024;

  const long long tile_m = (long long)blockIdx.y * 256;
  const long long tile_n = (long long)blockIdx.x * 256;

  const int tid  = threadIdx.x;
  const int wid  = tid >> 6;
  const int lane = tid & 63;
  const int srow = wid * 8 + (lane >> 3);
  const int scol = ((lane & 7) ^ (lane >> 3)) * 8;

  const __hip_bfloat16* aS = A + (tile_m + srow) * 1024 + scol;
  const __hip_bfloat16* bS = B + (tile_n + srow) * 1024 + scol;

  const int wm   = (wid >> 2) * 128;
  const int wn   = (wid & 3) * 64;
  const int quad = lane >> 4;
  const int l16  = lane & 15;
  const int sw   = l16 & 7;

  f32x4 acc[8][4];
  #pragma unroll
  for (int mi = 0; mi < 8; ++mi)
    #pragma unroll
    for (int ni = 0; ni < 4; ++ni)
      acc[mi][ni] = (f32x4){0.f, 0.f, 0.f, 0.f};

  mainloop256(aS, bS, &As[0][0], &Bs[0][0], wid, wm, wn, l16, quad, sw, acc);

  // epilogue: exp, bf16 store, per-wave 64-col row partials (32 per row total)
  __hip_bfloat16* C = Cout + (long long)bz * 2048 * 2048;
  #pragma unroll
  for (int mi = 0; mi < 8; ++mi) {
    #pragma unroll
    for (int r = 0; r < 4; ++r) {
      const long long row = tile_m + wm + mi * 16 + quad * 4 + r;
      float ssum = 0.f;
      #pragma unroll
      for (int ni = 0; ni < 4; ++ni) {
        const float e = __expf(acc[mi][ni][r]);
        const __hip_bfloat16 h = __float2bfloat16(e);
        C[row * 2048 + tile_n + wn + ni * 16 + l16] = h;
        ssum += __bfloat162float(h);
      }
      #pragma unroll
      for (int off = 1; off < 16; off <<= 1) ssum += __shfl_xor(ssum, off, 64);
      if (l16 == 0)
        part[((long long)bz * 2048 + row) * 32 + blockIdx.x * 4 + (wid & 3)] = ssum;
    }
  }
}

// ---------------- O = (P Vt^T) / rowsum, 128x64 tile, BK=64, swizzled ----------------
__global__ __launch_bounds__(256)
void gemm_pv(const __hip_bfloat16* __restrict__ A,     // expS [b][2048,2048]
             const __hip_bfloat16* __restrict__ B,     // Vt   [b][1024,2048]
             const float* __restrict__ part,           // [8192][32]
             float* __restrict__ Cout)                 // O    [b][2048,1024]
{
  __shared__ __align__(16) __hip_bfloat16 As[128 * 64];   // 16 KB
  __shared__ __align__(16) __hip_bfloat16 Bs[64 * 64];    // 8 KB
  __shared__ float rinv[128];

  const int K = 2048, N = 1024;
  const int bz = blockIdx.z;
  A += (long long)bz * 2048 * 2048;
  B += (long long)bz * 1024 * 2048;

  const long long tile_m = (long long)blockIdx.y * 128;
  const long long tile_n = (long long)blockIdx.x * 64;

  const int tid  = threadIdx.x;
  const int wid  = tid >> 6;
  const int lane = tid & 63;

  const int srow = wid * 8 + (lane >> 3);
  const int scol = (((lane & 7) ^ (lane >> 3))) * 8;

  const __hip_bfloat16* aptr = A + (tile_m + srow) * K + scol;
  const __hip_bfloat16* bptr = B + (tile_n + srow) * K + scol;
  char* la = (char*)As + (wid * 8) * 128;
  char* lb = (char*)Bs + (wid * 8) * 128;

  const int wm   = (wid >> 1) * 64;
  const int wn   = (wid & 1) * 32;
  const int quad = lane >> 4;
  const int l16  = lane & 15;
  const int sw   = l16 & 7;

  const bf16x8* Asv = (const bf16x8*)As;
  const bf16x8* Bsv = (const bf16x8*)Bs;

  f32x4 acc[4][2];
  #pragma unroll
  for (int mi = 0; mi < 4; ++mi)
    #pragma unroll
    for (int ni = 0; ni < 2; ++ni)
      acc[mi][ni] = (f32x4){0.f, 0.f, 0.f, 0.f};

  for (int k0 = 0; k0 < K; k0 += 64) {
    #pragma unroll
    for (int p = 0; p < 4; ++p)
      async_copy16(aptr + (long long)p * 32 * K, la + p * 32 * 128);
    #pragma unroll
    for (int p = 0; p < 2; ++p)
      async_copy16(bptr + (long long)p * 32 * K, lb + p * 32 * 128);
    aptr += 64;
    bptr += 64;
    __syncthreads();

    #pragma unroll
    for (int kk = 0; kk < 2; ++kk) {
      bf16x8 af[4], bfr[2];
      const int ch = (kk * 4 + quad);
      #pragma unroll
      for (int mi = 0; mi < 4; ++mi) af[mi]  = Asv[(wm + mi * 16 + l16) * 8 + (ch ^ sw)];
      #pragma unroll
      for (int ni = 0; ni < 2; ++ni) bfr[ni] = Bsv[(wn + ni * 16 + l16) * 8 + (ch ^ sw)];
      #pragma unroll
      for (int mi = 0; mi < 4; ++mi)
        #pragma unroll
        for (int ni = 0; ni < 2; ++ni)
          acc[mi][ni] = __builtin_amdgcn_mfma_f32_16x16x32_bf16(af[mi], bfr[ni], acc[mi][ni], 0, 0, 0);
    }
    __syncthreads();
  }

  // gather this tile's 128 row-sums (32 partials each), store reciprocal
  if (tid < 128) {
    const float4* pp = (const float4*)(part + ((long long)bz * 2048 + tile_m + tid) * 32);
    float s = 0.f;
    #pragma unroll
    for (int j = 0; j < 8; ++j) {
      const float4 f = pp[j];
      s += f.x + f.y + f.z + f.w;
    }
    rinv[tid] = 1.f / s;
  }
  __syncthreads();

  float* C = Cout + (long long)bz * 2048 * 1024;
  #pragma unroll
  for (int mi = 0; mi < 4; ++mi) {
    #pragma unroll
    for (int r = 0; r < 4; ++r) {
      const int rloc = wm + mi * 16 + quad * 4 + r;
      const float inv = rinv[rloc];
      const long long row = tile_m + rloc;
      #pragma unroll
      for (int ni = 0; ni < 2; ++ni) {
        const long long col = tile_n + wn + ni * 16 + l16;
        C[row * N + col] = acc[mi][ni][r] * inv;
      }
    }
  }
}

// ---------------- all casts in one dispatch ----------------
__global__ __launch_bounds__(256)
void cast_all(const float* __restrict__ x,
              const float* __restrict__ Wq, const float* __restrict__ Wk,
              const float* __restrict__ Wv,
              __hip_bfloat16* __restrict__ xb, __hip_bfloat16* __restrict__ wcat)
{
  const int bx = blockIdx.x;
  const float* src;
  __hip_bfloat16* dst;
  int i;
  if (bx < 8192) {                      // x: 2097152 float4s
    src = x; dst = xb; i = bx * 256 + threadIdx.x;
  } else {                              // weights: 262144 float4s each
    const int which = (bx - 8192) >> 10;
    src = (which == 0) ? Wq : (which == 1) ? Wk : Wv;
    dst = wcat + (long long)which * 1048576;
    i = ((bx - 8192) & 1023) * 256 + threadIdx.x;
  }
  const float4 f = ((const float4*)src)[i];
  union { ushort4 u; __hip_bfloat16 h[4]; } r;
  r.h[0] = __float2bfloat16(f.x);
  r.h[1] = __float2bfloat16(f.y);
  r.h[2] = __float2bfloat16(f.z);
  r.h[3] = __float2bfloat16(f.w);
  ((ushort4*)dst)[i] = r.u;
}

extern "C" void kernel_launch(void* const* d_in, const int* in_sizes, int n_in,
                              void* d_out, int out_size, void* d_ws, size_t ws_size,
                              hipStream_t stream)
{
  (void)in_sizes; (void)n_in; (void)out_size; (void)ws_size;

  const float* x  = (const float*)d_in[0];
  const float* Wq = (const float*)d_in[1];
  const float* Wk = (const float*)d_in[2];
  const float* Wv = (const float*)d_in[3];
  float* out = (float*)d_out;

  char* ws = (char*)d_ws;
  __hip_bfloat16* xb   = (__hip_bfloat16*)(ws);            // dead after qkv
  float*          part = (float*)(ws);                     // reuses xb region (1 MB)
  __hip_bfloat16* wcat = (__hip_bfloat16*)(ws + (16LL << 20));
  __hip_bfloat16* Q    = (__hip_bfloat16*)(ws + (22LL << 20));
  __hip_bfloat16* Kk   = (__hip_bfloat16*)(ws + (38LL << 20));
  __hip_bfloat16* Vt   = (__hip_bfloat16*)(ws + (54LL << 20));
  __hip_bfloat16* S    = (__hip_bfloat16*)(ws + (70LL << 20));

  cast_all<<<11264, 256, 0, stream>>>(x, Wq, Wk, Wv, xb, wcat);

  // fused QKV projection (256^2 8-phase); V lands transposed in Vt
  gemm_qkv<<<dim3(384, 1, 1), 512, 0, stream>>>(xb, wcat, Q, Kk, Vt);

  // S = exp(Q K^T) (256^2 8-phase), row-sum partials -> part (dead xb)
  gemm_s_exp<<<dim3(8, 8, 4), 512, 0, stream>>>(Q, Kk, S, part);

  // O = (P Vt^T) / rowsum -> fp32 d_out
  gemm_pv<<<dim3(16, 16, 4), 256, 0, stream>>>(S, Vt, part, out);
}

// Round 3
// 236.431 us; speedup vs baseline: 1.0439x; 1.0439x over previous
//
#include <hip/hip_runtime.h>
#include <hip/hip_bf16.h>
#include <stdint.h>

// ---------------------------------------------------------------------------
// Self-attention, single head, d=1024, seq=2048, batch=4, fp32 in/out.
// R10: R9 with the staging-schedule typo fixed: tile tb must restage
//      B(tb+2), not B(tb+3). R9 left every odd B-tile >=3 unstaged ->
//      absmax 0.12. Hazard audit of the rest of the R9 pipeline holds:
//      - gate queue at tile t end = B(t+1)[4], A(t+1)[4], B(t+2)[4];
//        vmcnt(4) completes exactly what tile t+1 reads.
//      - bfr reads drain before mid-barrier (lgkmcnt(4) covers the 4
//        oldest outstanding = bfr[2,3]); B(t+2) restage after it is safe.
//      - A(t+1) restage at R0 targets the buffer drained at the previous
//        end-barrier; per-wave vmcnt gate precedes the end barrier so
//        writes are visible to all reader waves.
//      Mainloop: 256x256/BK=64, 2 barriers per K-tile, A-frag register
//      prefetch under MFMA, counted vmcnt, setprio around MFMA clusters.
//      pv: 128x128 tiles, grid 8x16x4=512 (2 balanced rounds, 32KB LDS).
// Pipeline: cast_all | QKV = xb @ wcat^T (Q/32, V->Vt scatter) |
//           S = exp(QK^T) + rowsum partials | O = (P Vt^T)/rowsum
// Workspace (102 MiB): xb @ 0 (16; 1st MiB reused as part after qkv)
//   wcat @ 16 (6)  Q @ 22 (16)  K @ 38 (16)  Vt @ 54 (16)  S @ 70 (32)
// ---------------------------------------------------------------------------

typedef __attribute__((ext_vector_type(8))) short bf16x8;   // 8 bf16 = 4 VGPRs
typedef __attribute__((ext_vector_type(4))) float f32x4;

__device__ __forceinline__ void async_copy16(const void* g, void* l) {
  __builtin_amdgcn_global_load_lds(
      (__attribute__((address_space(1))) void*)(g),
      (__attribute__((address_space(3))) void*)(l),
      16, 0, 0);
}

// ---- 256x256 / BK=64 / 2-barrier-per-tile pipelined mainloop, K=1024 ----
// aS/bS: per-lane staging source = Op + (tile_base + srow)*1024 + scol
// As/Bs: LDS [2][256*64] bf16 (32768 B per buffer)
__device__ __forceinline__ void mainloop256(
    const __hip_bfloat16* __restrict__ aS,
    const __hip_bfloat16* __restrict__ bS,
    __hip_bfloat16* As, __hip_bfloat16* Bs,
    const int wid, const int wm, const int wn,
    const int l16, const int quad, const int sw,
    f32x4 (&acc)[8][4])
{
  const bf16x8* Av = (const bf16x8*)As;
  const bf16x8* Bv = (const bf16x8*)Bs;
  char* lA = (char*)As + wid * 1024;     // wave-uniform stage base
  char* lB = (char*)Bs + wid * 1024;
  bf16x8 bfr[4][2];                      // B frags, held across the tile
  bf16x8 afc[2][2], afn[2][2];           // A frags: current / next phase

#define SB0 __builtin_amdgcn_sched_barrier(0)

#define STG_A2(t) do { \
    async_copy16(aS + ((t)*64 +        0), lA + ((t)&1)*32768 +        0); \
    async_copy16(aS + ((t)*64 +  64*1024), lA + ((t)&1)*32768 +  64*128); \
    async_copy16(aS + ((t)*64 + 128*1024), lA + ((t)&1)*32768 + 128*128); \
    async_copy16(aS + ((t)*64 + 192*1024), lA + ((t)&1)*32768 + 192*128); \
  } while (0)
#define STG_B2(t) do { \
    async_copy16(bS + ((t)*64 +        0), lB + ((t)&1)*32768 +        0); \
    async_copy16(bS + ((t)*64 +  64*1024), lB + ((t)&1)*32768 +  64*128); \
    async_copy16(bS + ((t)*64 + 128*1024), lB + ((t)&1)*32768 + 128*128); \
    async_copy16(bS + ((t)*64 + 192*1024), lB + ((t)&1)*32768 + 192*128); \
  } while (0)

#define RD_AF(dst, t, phi) do { \
    _Pragma("unroll") \
    for (int m2 = 0; m2 < 2; ++m2) \
      _Pragma("unroll") \
      for (int kk = 0; kk < 2; ++kk) \
        dst[m2][kk] = Av[((t)&1)*2048 + (wm + ((phi)*2 + m2)*16 + l16)*8 + ((kk*4 + quad) ^ sw)]; \
  } while (0)
#define RD_BF(t, nlo, nhi) do { \
    _Pragma("unroll") \
    for (int ni = (nlo); ni < (nhi); ++ni) \
      _Pragma("unroll") \
      for (int kk = 0; kk < 2; ++kk) \
        bfr[ni][kk] = Bv[((t)&1)*2048 + (wn + ni*16 + l16)*8 + ((kk*4 + quad) ^ sw)]; \
  } while (0)
#define MM(src, phi, nlo, nhi) do { \
    _Pragma("unroll") \
    for (int kk = 0; kk < 2; ++kk) \
      _Pragma("unroll") \
      for (int m2 = 0; m2 < 2; ++m2) \
        _Pragma("unroll") \
        for (int ni = (nlo); ni < (nhi); ++ni) \
          acc[(phi)*2 + m2][ni] = __builtin_amdgcn_mfma_f32_16x16x32_bf16( \
              src[m2][kk], bfr[ni][kk], acc[(phi)*2 + m2][ni], 0, 0, 0); \
  } while (0)

  // One K-tile t. STG0 = A(t+1) staging (ph0 slot), STG1 = B(t+2) (ph1 slot),
  // GATE = vmcnt wait covering A(t+1)+B(t+1) before the end barrier.
#define TILE(t, STG0_STMT, STG1_STMT, GATE_STMT) do { \
    /* R0 (after prev end-barrier): boundary reads + A-restage issue */ \
    RD_BF(t, 0, 2); \
    RD_AF(afc, t, 0); \
    STG0_STMT; \
    asm volatile("s_waitcnt lgkmcnt(0)"); SB0; \
    RD_BF(t, 2, 4); \
    SB0; \
    RD_AF(afn, t, 1); \
    SB0; \
    __builtin_amdgcn_s_setprio(1); MM(afc, 0, 0, 2); __builtin_amdgcn_s_setprio(0); \
    asm volatile("s_waitcnt lgkmcnt(4)"); SB0; \
    __builtin_amdgcn_s_setprio(1); MM(afc, 0, 2, 4); __builtin_amdgcn_s_setprio(0); \
    SB0; \
    __builtin_amdgcn_s_barrier();   /* all B-buf(t) reads drained chip-wide */ \
    /* R1: B(t+2) restage + MFMA ph1 (afn), prefetch ph2 */ \
    STG1_STMT; \
    asm volatile("s_waitcnt lgkmcnt(0)"); SB0; \
    RD_AF(afc, t, 2); \
    SB0; \
    __builtin_amdgcn_s_setprio(1); MM(afn, 1, 0, 4); __builtin_amdgcn_s_setprio(0); \
    /* R2: MFMA ph2 (afc), prefetch ph3 */ \
    asm volatile("s_waitcnt lgkmcnt(0)"); SB0; \
    RD_AF(afn, t, 3); \
    SB0; \
    __builtin_amdgcn_s_setprio(1); MM(afc, 2, 0, 4); __builtin_amdgcn_s_setprio(0); \
    /* R3: MFMA ph3 (afn), gate, publish */ \
    asm volatile("s_waitcnt lgkmcnt(0)"); SB0; \
    __builtin_amdgcn_s_setprio(1); MM(afn, 3, 0, 4); __builtin_amdgcn_s_setprio(0); \
    GATE_STMT; \
    SB0; \
    __builtin_amdgcn_s_barrier(); \
  } while (0)

#define GATE4 asm volatile("s_waitcnt vmcnt(4)")
#define GATE0 asm volatile("s_waitcnt vmcnt(0)")
#define GNONE (void)0

  // prologue: B(0), A(0), B(1); keep B(1)'s 4 loads outstanding
  STG_B2(0); STG_A2(0); STG_B2(1);
  asm volatile("s_waitcnt vmcnt(4)");
  __builtin_amdgcn_s_barrier();

  // tiles 0..13: uniform slots {ph0: A(t+1)x2, ph1: B(t+2)x2}, gate vmcnt(4).
  // At gate of tile t, outstanding (oldest->newest) = B(t+1)[4], A(t+1)[4],
  // B(t+2)[4] = 12 insts -> vmcnt(4) completes A(t+1)+B(t+1), keeps B(t+2).
  #pragma unroll 1
  for (int i = 0; i < 7; ++i) {
    const int ta = 2 * i, tb = 2 * i + 1;
    TILE(ta, STG_A2(tb),     STG_B2(ta + 2), GATE4);
    TILE(tb, STG_A2(ta + 2), STG_B2(tb + 2), GATE4);
  }
  // peeled: tile 14 stages only A(15); tile 15 stages nothing.
  TILE(14, STG_A2(15), GNONE, GATE0);
  TILE(15, GNONE,      GNONE, GNONE);

#undef TILE
#undef GATE4
#undef GATE0
#undef GNONE
#undef MM
#undef RD_BF
#undef RD_AF
#undef STG_A2
#undef STG_B2
#undef SB0
}

// ---------------- fused QKV projection, 256x256 pipelined ----------------
// A = xb [8192,1024], B = wcat [3072,1024] (Wq | Wk | Wv rows)
// Q,K -> [8192,1024] bf16 (Q/32); V -> Vt [4][1024][2048] via 8B scatter.
__global__ __launch_bounds__(512, 2)
void gemm_qkv(const __hip_bfloat16* __restrict__ A,
              const __hip_bfloat16* __restrict__ B,
              __hip_bfloat16* __restrict__ Q,
              __hip_bfloat16* __restrict__ Kk,
              __hip_bfloat16* __restrict__ Vt)
{
  __shared__ __align__(16) __hip_bfloat16 As[2][256 * 64];   // 64 KB
  __shared__ __align__(16) __hip_bfloat16 Bs[2][256 * 64];   // 64 KB

  // XCD-chunked bijective swizzle: 384 blocks = 8 * 48; same-XCD blocks
  // share 4 consecutive tile_m panels (A reuse in per-XCD L2).
  const int bid = blockIdx.x;
  const int s   = (bid & 7) * 48 + (bid >> 3);
  const long long tile_m = (long long)(s / 12) * 256;
  const long long tile_n = (long long)(s % 12) * 256;

  const int tid  = threadIdx.x;
  const int wid  = tid >> 6;
  const int lane = tid & 63;
  const int srow = wid * 8 + (lane >> 3);
  const int scol = ((lane & 7) ^ (lane >> 3)) * 8;   // swizzled source chunk

  const __hip_bfloat16* aS = A + (tile_m + srow) * 1024 + scol;
  const __hip_bfloat16* bS = B + (tile_n + srow) * 1024 + scol;

  const int wm   = (wid >> 2) * 128;
  const int wn   = (wid & 3) * 64;
  const int quad = lane >> 4;
  const int l16  = lane & 15;
  const int sw   = l16 & 7;

  f32x4 acc[8][4];
  #pragma unroll
  for (int mi = 0; mi < 8; ++mi)
    #pragma unroll
    for (int ni = 0; ni < 4; ++ni)
      acc[mi][ni] = (f32x4){0.f, 0.f, 0.f, 0.f};

  mainloop256(aS, bS, &As[0][0], &Bs[0][0], wid, wm, wn, l16, quad, sw, acc);

  const int mat = (int)(tile_n >> 10);
  if (mat < 2) {
    // Q / K direct write.  C/D layout (m89/m91): col = l16, row = quad*4 + r
    __hip_bfloat16* outp = (mat == 0) ? Q : Kk;
    const float scale = (mat == 0) ? 0.03125f : 1.0f;   // 1/sqrt(1024) in Q
    const int coln0 = (int)(tile_n & 1023);
    #pragma unroll
    for (int mi = 0; mi < 8; ++mi) {
      #pragma unroll
      for (int r = 0; r < 4; ++r) {
        const long long row = tile_m + wm + mi * 16 + quad * 4 + r;
        #pragma unroll
        for (int ni = 0; ni < 4; ++ni) {
          const int col = coln0 + wn + ni * 16 + l16;
          outp[row * 1024 + col] = __float2bfloat16(acc[mi][ni][r] * scale);
        }
      }
    }
  } else {
    // V: lane's 4 r-values are seq-consecutive -> one 8B store per (mi,ni).
    const int b    = (int)(tile_m >> 11);
    const int seq0 = (int)(tile_m & 2047);
    const int d0   = (int)(tile_n - 2048);
    #pragma unroll
    for (int mi = 0; mi < 8; ++mi) {
      const int seq = seq0 + wm + mi * 16 + quad * 4;
      #pragma unroll
      for (int ni = 0; ni < 4; ++ni) {
        const int d = d0 + wn + ni * 16 + l16;
        union { ushort4 u; unsigned short sh[4]; } pk;
        #pragma unroll
        for (int r = 0; r < 4; ++r)
          pk.sh[r] = __bfloat16_as_ushort(__float2bfloat16(acc[mi][ni][r]));
        *(ushort4*)(Vt + ((long long)(b * 1024 + d)) * 2048 + seq) = pk.u;
      }
    }
  }
}

// ---------------- S = exp(Q K^T) + row-sum partials, 256x256 pipelined ----------------
__global__ __launch_bounds__(512, 2)
void gemm_s_exp(const __hip_bfloat16* __restrict__ A,
                const __hip_bfloat16* __restrict__ B,
                __hip_bfloat16* __restrict__ Cout,
                float* __restrict__ part)
{
  __shared__ __align__(16) __hip_bfloat16 As[2][256 * 64];   // 64 KB
  __shared__ __align__(16) __hip_bfloat16 Bs[2][256 * 64];   // 64 KB

  const int bz = blockIdx.z;
  A += (long long)bz * 2048 * 1024;
  B += (long long)bz * 2048 * 1024;

  const long long tile_m = (long long)blockIdx.y * 256;
  const long long tile_n = (long long)blockIdx.x * 256;

  const int tid  = threadIdx.x;
  const int wid  = tid >> 6;
  const int lane = tid & 63;
  const int srow = wid * 8 + (lane >> 3);
  const int scol = ((lane & 7) ^ (lane >> 3)) * 8;

  const __hip_bfloat16* aS = A + (tile_m + srow) * 1024 + scol;
  const __hip_bfloat16* bS = B + (tile_n + srow) * 1024 + scol;

  const int wm   = (wid >> 2) * 128;
  const int wn   = (wid & 3) * 64;
  const int quad = lane >> 4;
  const int l16  = lane & 15;
  const int sw   = l16 & 7;

  f32x4 acc[8][4];
  #pragma unroll
  for (int mi = 0; mi < 8; ++mi)
    #pragma unroll
    for (int ni = 0; ni < 4; ++ni)
      acc[mi][ni] = (f32x4){0.f, 0.f, 0.f, 0.f};

  mainloop256(aS, bS, &As[0][0], &Bs[0][0], wid, wm, wn, l16, quad, sw, acc);

  // epilogue: exp, bf16 store, per-wave 64-col row partials (32 per row total)
  __hip_bfloat16* C = Cout + (long long)bz * 2048 * 2048;
  #pragma unroll
  for (int mi = 0; mi < 8; ++mi) {
    #pragma unroll
    for (int r = 0; r < 4; ++r) {
      const long long row = tile_m + wm + mi * 16 + quad * 4 + r;
      float ssum = 0.f;
      #pragma unroll
      for (int ni = 0; ni < 4; ++ni) {
        const float e = __expf(acc[mi][ni][r]);
        const __hip_bfloat16 h = __float2bfloat16(e);
        C[row * 2048 + tile_n + wn + ni * 16 + l16] = h;
        ssum += __bfloat162float(h);
      }
      #pragma unroll
      for (int off = 1; off < 16; off <<= 1) ssum += __shfl_xor(ssum, off, 64);
      if (l16 == 0)
        part[((long long)bz * 2048 + row) * 32 + blockIdx.x * 4 + (wid & 3)] = ssum;
    }
  }
}

// ---------------- O = (P Vt^T) / rowsum, 128x128 tile, BK=64, swizzled ----------------
__global__ __launch_bounds__(256)
void gemm_pv(const __hip_bfloat16* __restrict__ A,     // expS [b][2048,2048]
             const __hip_bfloat16* __restrict__ B,     // Vt   [b][1024,2048]
             const float* __restrict__ part,           // [8192][32]
             float* __restrict__ Cout)                 // O    [b][2048,1024]
{
  __shared__ __align__(16) __hip_bfloat16 As[128 * 64];   // 16 KB
  __shared__ __align__(16) __hip_bfloat16 Bs[128 * 64];   // 16 KB
  __shared__ float rinv[128];

  const int K = 2048, N = 1024;
  const int bz = blockIdx.z;
  A += (long long)bz * 2048 * 2048;
  B += (long long)bz * 1024 * 2048;

  const long long tile_m = (long long)blockIdx.y * 128;
  const long long tile_n = (long long)blockIdx.x * 128;

  const int tid  = threadIdx.x;
  const int wid  = tid >> 6;
  const int lane = tid & 63;

  const int srow = wid * 8 + (lane >> 3);
  const int scol = (((lane & 7) ^ (lane >> 3))) * 8;

  const __hip_bfloat16* aptr = A + (tile_m + srow) * K + scol;
  const __hip_bfloat16* bptr = B + (tile_n + srow) * K + scol;
  char* la = (char*)As + (wid * 8) * 128;
  char* lb = (char*)Bs + (wid * 8) * 128;

  const int wm   = (wid >> 1) * 64;
  const int wn   = (wid & 1) * 64;
  const int quad = lane >> 4;
  const int l16  = lane & 15;
  const int sw   = l16 & 7;

  const bf16x8* Asv = (const bf16x8*)As;
  const bf16x8* Bsv = (const bf16x8*)Bs;

  f32x4 acc[4][4];
  #pragma unroll
  for (int mi = 0; mi < 4; ++mi)
    #pragma unroll
    for (int ni = 0; ni < 4; ++ni)
      acc[mi][ni] = (f32x4){0.f, 0.f, 0.f, 0.f};

  for (int k0 = 0; k0 < K; k0 += 64) {
    #pragma unroll
    for (int p = 0; p < 4; ++p)
      async_copy16(aptr + (long long)p * 32 * K, la + p * 32 * 128);
    #pragma unroll
    for (int p = 0; p < 4; ++p)
      async_copy16(bptr + (long long)p * 32 * K, lb + p * 32 * 128);
    aptr += 64;
    bptr += 64;
    __syncthreads();

    #pragma unroll
    for (int kk = 0; kk < 2; ++kk) {
      bf16x8 af[4], bfr[4];
      const int ch = (kk * 4 + quad);
      #pragma unroll
      for (int mi = 0; mi < 4; ++mi) af[mi]  = Asv[(wm + mi * 16 + l16) * 8 + (ch ^ sw)];
      #pragma unroll
      for (int ni = 0; ni < 4; ++ni) bfr[ni] = Bsv[(wn + ni * 16 + l16) * 8 + (ch ^ sw)];
      #pragma unroll
      for (int mi = 0; mi < 4; ++mi)
        #pragma unroll
        for (int ni = 0; ni < 4; ++ni)
          acc[mi][ni] = __builtin_amdgcn_mfma_f32_16x16x32_bf16(af[mi], bfr[ni], acc[mi][ni], 0, 0, 0);
    }
    __syncthreads();
  }

  // gather this tile's 128 row-sums (32 partials each), store reciprocal
  if (tid < 128) {
    const float4* pp = (const float4*)(part + ((long long)bz * 2048 + tile_m + tid) * 32);
    float s = 0.f;
    #pragma unroll
    for (int j = 0; j < 8; ++j) {
      const float4 f = pp[j];
      s += f.x + f.y + f.z + f.w;
    }
    rinv[tid] = 1.f / s;
  }
  __syncthreads();

  float* C = Cout + (long long)bz * 2048 * 1024;
  #pragma unroll
  for (int mi = 0; mi < 4; ++mi) {
    #pragma unroll
    for (int r = 0; r < 4; ++r) {
      const int rloc = wm + mi * 16 + quad * 4 + r;
      const float inv = rinv[rloc];
      const long long row = tile_m + rloc;
      #pragma unroll
      for (int ni = 0; ni < 4; ++ni) {
        const long long col = tile_n + wn + ni * 16 + l16;
        C[row * N + col] = acc[mi][ni][r] * inv;
      }
    }
  }
}

// ---------------- all casts in one dispatch ----------------
__global__ __launch_bounds__(256)
void cast_all(const float* __restrict__ x,
              const float* __restrict__ Wq, const float* __restrict__ Wk,
              const float* __restrict__ Wv,
              __hip_bfloat16* __restrict__ xb, __hip_bfloat16* __restrict__ wcat)
{
  const int bx = blockIdx.x;
  const float* src;
  __hip_bfloat16* dst;
  int i;
  if (bx < 8192) {                      // x: 2097152 float4s
    src = x; dst = xb; i = bx * 256 + threadIdx.x;
  } else {                              // weights: 262144 float4s each
    const int which = (bx - 8192) >> 10;
    src = (which == 0) ? Wq : (which == 1) ? Wk : Wv;
    dst = wcat + (long long)which * 1048576;
    i = ((bx - 8192) & 1023) * 256 + threadIdx.x;
  }
  const float4 f = ((const float4*)src)[i];
  union { ushort4 u; __hip_bfloat16 h[4]; } r;
  r.h[0] = __float2bfloat16(f.x);
  r.h[1] = __float2bfloat16(f.y);
  r.h[2] = __float2bfloat16(f.z);
  r.h[3] = __float2bfloat16(f.w);
  ((ushort4*)dst)[i] = r.u;
}

extern "C" void kernel_launch(void* const* d_in, const int* in_sizes, int n_in,
                              void* d_out, int out_size, void* d_ws, size_t ws_size,
                              hipStream_t stream)
{
  (void)in_sizes; (void)n_in; (void)out_size; (void)ws_size;

  const float* x  = (const float*)d_in[0];
  const float* Wq = (const float*)d_in[1];
  const float* Wk = (const float*)d_in[2];
  const float* Wv = (const float*)d_in[3];
  float* out = (float*)d_out;

  char* ws = (char*)d_ws;
  __hip_bfloat16* xb   = (__hip_bfloat16*)(ws);            // dead after qkv
  float*          part = (float*)(ws);                     // reuses xb region (1 MB)
  __hip_bfloat16* wcat = (__hip_bfloat16*)(ws + (16LL << 20));
  __hip_bfloat16* Q    = (__hip_bfloat16*)(ws + (22LL << 20));
  __hip_bfloat16* Kk   = (__hip_bfloat16*)(ws + (38LL << 20));
  __hip_bfloat16* Vt   = (__hip_bfloat16*)(ws + (54LL << 20));
  __hip_bfloat16* S    = (__hip_bfloat16*)(ws + (70LL << 20));

  cast_all<<<11264, 256, 0, stream>>>(x, Wq, Wk, Wv, xb, wcat);

  // fused QKV projection (256^2 pipelined); V lands transposed in Vt
  gemm_qkv<<<dim3(384, 1, 1), 512, 0, stream>>>(xb, wcat, Q, Kk, Vt);

  // S = exp(Q K^T) (256^2 pipelined), row-sum partials -> part (dead xb)
  gemm_s_exp<<<dim3(8, 8, 4), 512, 0, stream>>>(Q, Kk, S, part);

  // O = (P Vt^T) / rowsum -> fp32 d_out
  gemm_pv<<<dim3(8, 16, 4), 256, 0, stream>>>(S, Vt, part, out);
}

// Round 5
// 234.290 us; speedup vs baseline: 1.0535x; 1.0091x over previous
//
#include <hip/hip_runtime.h>
#include <hip/hip_bf16.h>
#include <stdint.h>

// ---------------------------------------------------------------------------
// Self-attention, single head, d=1024, seq=2048, batch=4, fp32 in/out.
// R12: R11 with the B-staging template bug fixed: STG_B2 must issue NI
//      lines (BN = NI*64 rows, 64 rows per global_load_lds line), not NI/2.
//      R11 left the upper half of every B tile unstaged -> NaN. Corrected
//      gate audit (line counts B=NI, A=4):
//        NI=4: gate queue B(t+1)[4] A(t+1)[4] B(t+2)[4] -> vmcnt(4)  (==R10)
//        NI=2: gate queue B(t+1)[2] A(t+1)[4] B(t+2)[2] -> vmcnt(2)
//        lgkmcnt(4) completes the bfr-hi reads in both instantiations.
//      Grid plan (every GEMM = 256 blocks = 1.0 rounds):
//        gemm_qk   : Q,K proj, 32x8 tiles of 256x256   (NI=4)
//        gemm_v    : V proj,   32x8 tiles of 256x128   (NI=2)
//        gemm_s_exp: 8x8x4 tiles of 256x256            (NI=4)
//        gemm_pv   : 8x8x4 tiles of 256x128, NT=32     (NI=2)
// Pipeline: cast_all | QK proj | V proj (-> Vt scatter) |
//           S = exp(QK^T) + rowsum partials | O = (P Vt^T)/rowsum
// Workspace (102 MiB): xb @ 0 (16; 1st MiB reused as part after v)
//   wcat @ 16 (6)  Q @ 22 (16)  K @ 38 (16)  Vt @ 54 (16)  S @ 70 (32)
// ---------------------------------------------------------------------------

typedef __attribute__((ext_vector_type(8))) short bf16x8;   // 8 bf16 = 4 VGPRs
typedef __attribute__((ext_vector_type(4))) float f32x4;

__device__ __forceinline__ void async_copy16(const void* g, void* l) {
  __builtin_amdgcn_global_load_lds(
      (__attribute__((address_space(1))) void*)(g),
      (__attribute__((address_space(3))) void*)(l),
      16, 0, 0);
}

// ---- 256xBN / BK=64 / 2-barrier-per-tile pipelined mainloop ----
// NI: B-frags per wave (4 -> BN=256, 2 -> BN=128). NT: K/64. KS: row stride.
// aS/bS: per-lane staging source = Op + (tile_base + srow)*KS + scol
// As: LDS [2][256*64] bf16 (32KB/buf). Bs: LDS [2][NI*64*64] (NI*8KB/buf).
template<int NI, int NT, int KS>
__device__ __forceinline__ void mainloop256(
    const __hip_bfloat16* __restrict__ aS,
    const __hip_bfloat16* __restrict__ bS,
    __hip_bfloat16* As, __hip_bfloat16* Bs,
    const int wid, const int wm, const int wn,
    const int l16, const int quad, const int sw,
    f32x4 (&acc)[8][NI])
{
  constexpr int NI2 = NI / 2;
  const bf16x8* Av = (const bf16x8*)As;
  const bf16x8* Bv = (const bf16x8*)Bs;
  char* lA = (char*)As + wid * 1024;     // wave-uniform stage base
  char* lB = (char*)Bs + wid * 1024;
  bf16x8 bfr[NI][2];                     // B frags, held across the tile
  bf16x8 afc[2][2], afn[2][2];           // A frags: current / next phase

#define SB0 __builtin_amdgcn_sched_barrier(0)

#define STG_A2(t) do { \
    _Pragma("unroll") \
    for (int p = 0; p < 4; ++p) \
      async_copy16(aS + ((t)*64 + (long long)p * 64 * KS), \
                   lA + ((t)&1)*32768 + p * 64 * 128); \
  } while (0)
#define STG_B2(t) do { \
    _Pragma("unroll") \
    for (int p = 0; p < NI; ++p) \
      async_copy16(bS + ((t)*64 + (long long)p * 64 * KS), \
                   lB + ((t)&1)*(NI*8192) + p * 64 * 128); \
  } while (0)

#define RD_AF(dst, t, phi) do { \
    _Pragma("unroll") \
    for (int m2 = 0; m2 < 2; ++m2) \
      _Pragma("unroll") \
      for (int kk = 0; kk < 2; ++kk) \
        dst[m2][kk] = Av[((t)&1)*2048 + (wm + ((phi)*2 + m2)*16 + l16)*8 + ((kk*4 + quad) ^ sw)]; \
  } while (0)
#define RD_BF(t, nlo, nhi) do { \
    _Pragma("unroll") \
    for (int ni = (nlo); ni < (nhi); ++ni) \
      _Pragma("unroll") \
      for (int kk = 0; kk < 2; ++kk) \
        bfr[ni][kk] = Bv[((t)&1)*(NI*512) + (wn + ni*16 + l16)*8 + ((kk*4 + quad) ^ sw)]; \
  } while (0)
#define MM(src, phi, nlo, nhi) do { \
    _Pragma("unroll") \
    for (int kk = 0; kk < 2; ++kk) \
      _Pragma("unroll") \
      for (int m2 = 0; m2 < 2; ++m2) \
        _Pragma("unroll") \
        for (int ni = (nlo); ni < (nhi); ++ni) \
          acc[(phi)*2 + m2][ni] = __builtin_amdgcn_mfma_f32_16x16x32_bf16( \
              src[m2][kk], bfr[ni][kk], acc[(phi)*2 + m2][ni], 0, 0, 0); \
  } while (0)

  // One K-tile t. STG0 = A(t+1) staging (ph0 slot), STG1 = B(t+2) (ph1 slot),
  // GATE = vmcnt wait covering A(t+1)+B(t+1) before the end barrier.
#define TILE(t, STG0_STMT, STG1_STMT, GATE_STMT) do { \
    /* R0 (after prev end-barrier): boundary reads + A-restage issue */ \
    RD_BF(t, 0, NI2); \
    RD_AF(afc, t, 0); \
    STG0_STMT; \
    asm volatile("s_waitcnt lgkmcnt(0)"); SB0; \
    RD_BF(t, NI2, NI); \
    SB0; \
    RD_AF(afn, t, 1); \
    SB0; \
    __builtin_amdgcn_s_setprio(1); MM(afc, 0, 0, NI2); __builtin_amdgcn_s_setprio(0); \
    asm volatile("s_waitcnt lgkmcnt(4)"); SB0; \
    __builtin_amdgcn_s_setprio(1); MM(afc, 0, NI2, NI); __builtin_amdgcn_s_setprio(0); \
    SB0; \
    __builtin_amdgcn_s_barrier();   /* all B-buf(t) reads drained chip-wide */ \
    /* R1: B(t+2) restage + MFMA ph1 (afn), prefetch ph2 */ \
    STG1_STMT; \
    asm volatile("s_waitcnt lgkmcnt(0)"); SB0; \
    RD_AF(afc, t, 2); \
    SB0; \
    __builtin_amdgcn_s_setprio(1); MM(afn, 1, 0, NI); __builtin_amdgcn_s_setprio(0); \
    /* R2: MFMA ph2 (afc), prefetch ph3 */ \
    asm volatile("s_waitcnt lgkmcnt(0)"); SB0; \
    RD_AF(afn, t, 3); \
    SB0; \
    __builtin_amdgcn_s_setprio(1); MM(afc, 2, 0, NI); __builtin_amdgcn_s_setprio(0); \
    /* R3: MFMA ph3 (afn), gate, publish */ \
    asm volatile("s_waitcnt lgkmcnt(0)"); SB0; \
    __builtin_amdgcn_s_setprio(1); MM(afn, 3, 0, NI); __builtin_amdgcn_s_setprio(0); \
    GATE_STMT; \
    SB0; \
    __builtin_amdgcn_s_barrier(); \
  } while (0)

  // gate literal = B line count of the newest (kept-in-flight) B stage
#define GATEN do { if constexpr (NI == 4) asm volatile("s_waitcnt vmcnt(4)"); \
                   else                   asm volatile("s_waitcnt vmcnt(2)"); } while (0)
#define GATE0 asm volatile("s_waitcnt vmcnt(0)")
#define GNONE (void)0

  // prologue: B(0), A(0), B(1); keep B(1)'s lines outstanding
  STG_B2(0); STG_A2(0); STG_B2(1);
  GATEN;
  __builtin_amdgcn_s_barrier();

  // tiles 0..NT-3: uniform slots {R0: A(t+1), R1: B(t+2)}, gate per tile.
  #pragma unroll 1
  for (int i = 0; i < NT / 2 - 1; ++i) {
    const int ta = 2 * i, tb = 2 * i + 1;
    TILE(ta, STG_A2(tb),     STG_B2(ta + 2), GATEN);
    TILE(tb, STG_A2(ta + 2), STG_B2(tb + 2), GATEN);
  }
  // peeled: tile NT-2 stages only A(NT-1); tile NT-1 stages nothing.
  TILE(NT - 2, STG_A2(NT - 1), GNONE, GATE0);
  TILE(NT - 1, GNONE,          GNONE, GNONE);

#undef TILE
#undef GATEN
#undef GATE0
#undef GNONE
#undef MM
#undef RD_BF
#undef RD_AF
#undef STG_A2
#undef STG_B2
#undef SB0
}

// ---------------- Q,K projection, 256x256, grid 256 ----------------
// A = xb [8192,1024], B = wcat rows 0..2047 (Wq | Wk)
__global__ __launch_bounds__(512, 2)
void gemm_qk(const __hip_bfloat16* __restrict__ A,
             const __hip_bfloat16* __restrict__ B,
             __hip_bfloat16* __restrict__ Q,
             __hip_bfloat16* __restrict__ Kk)
{
  __shared__ __align__(16) __hip_bfloat16 As[2][256 * 64];   // 64 KB
  __shared__ __align__(16) __hip_bfloat16 Bs[2][256 * 64];   // 64 KB

  // XCD-chunked bijective swizzle: 256 = 8 XCD * 32; same-XCD blocks span
  // 4 consecutive tile_m panels x 8 tile_n (A-panel reuse in per-XCD L2).
  const int bid = blockIdx.x;
  const int s   = (bid & 7) * 32 + (bid >> 3);
  const long long tile_m = (long long)(s >> 3) * 256;
  const long long tile_n = (long long)(s & 7) * 256;

  const int tid  = threadIdx.x;
  const int wid  = tid >> 6;
  const int lane = tid & 63;
  const int srow = wid * 8 + (lane >> 3);
  const int scol = ((lane & 7) ^ (lane >> 3)) * 8;   // swizzled source chunk

  const __hip_bfloat16* aS = A + (tile_m + srow) * 1024 + scol;
  const __hip_bfloat16* bS = B + (tile_n + srow) * 1024 + scol;

  const int wm   = (wid >> 2) * 128;
  const int wn   = (wid & 3) * 64;
  const int quad = lane >> 4;
  const int l16  = lane & 15;
  const int sw   = l16 & 7;

  f32x4 acc[8][4];
  #pragma unroll
  for (int mi = 0; mi < 8; ++mi)
    #pragma unroll
    for (int ni = 0; ni < 4; ++ni)
      acc[mi][ni] = (f32x4){0.f, 0.f, 0.f, 0.f};

  mainloop256<4, 16, 1024>(aS, bS, &As[0][0], &Bs[0][0],
                           wid, wm, wn, l16, quad, sw, acc);

  // C/D layout (m89/m91): col = l16, row = quad*4 + r
  const int mat = (int)(tile_n >> 10);
  __hip_bfloat16* outp = (mat == 0) ? Q : Kk;
  const float scale = (mat == 0) ? 0.03125f : 1.0f;   // 1/sqrt(1024) in Q
  const int coln0 = (int)(tile_n & 1023);
  #pragma unroll
  for (int mi = 0; mi < 8; ++mi) {
    #pragma unroll
    for (int r = 0; r < 4; ++r) {
      const long long row = tile_m + wm + mi * 16 + quad * 4 + r;
      #pragma unroll
      for (int ni = 0; ni < 4; ++ni) {
        const int col = coln0 + wn + ni * 16 + l16;
        outp[row * 1024 + col] = __float2bfloat16(acc[mi][ni][r] * scale);
      }
    }
  }
}

// ---------------- V projection, 256x128, grid 256 ----------------
// A = xb [8192,1024], B = Wv rows.  V -> Vt [4][1024][2048] via 8B scatter.
__global__ __launch_bounds__(512, 2)
void gemm_v(const __hip_bfloat16* __restrict__ A,
            const __hip_bfloat16* __restrict__ B,
            __hip_bfloat16* __restrict__ Vt)
{
  __shared__ __align__(16) __hip_bfloat16 As[2][256 * 64];   // 64 KB
  __shared__ __align__(16) __hip_bfloat16 Bs[2][128 * 64];   // 32 KB

  const int bid = blockIdx.x;
  const int s   = (bid & 7) * 32 + (bid >> 3);
  const long long tile_m = (long long)(s >> 3) * 256;
  const long long tile_n = (long long)(s & 7) * 128;

  const int tid  = threadIdx.x;
  const int wid  = tid >> 6;
  const int lane = tid & 63;
  const int srow = wid * 8 + (lane >> 3);
  const int scol = ((lane & 7) ^ (lane >> 3)) * 8;

  const __hip_bfloat16* aS = A + (tile_m + srow) * 1024 + scol;
  const __hip_bfloat16* bS = B + (tile_n + srow) * 1024 + scol;

  const int wm   = (wid >> 2) * 128;
  const int wn   = (wid & 3) * 32;
  const int quad = lane >> 4;
  const int l16  = lane & 15;
  const int sw   = l16 & 7;

  f32x4 acc[8][2];
  #pragma unroll
  for (int mi = 0; mi < 8; ++mi)
    #pragma unroll
    for (int ni = 0; ni < 2; ++ni)
      acc[mi][ni] = (f32x4){0.f, 0.f, 0.f, 0.f};

  mainloop256<2, 16, 1024>(aS, bS, &As[0][0], &Bs[0][0],
                           wid, wm, wn, l16, quad, sw, acc);

  // V: lane's 4 r-values are seq-consecutive -> one 8B store per (mi,ni).
  const int b    = (int)(tile_m >> 11);
  const int seq0 = (int)(tile_m & 2047);
  const int d0   = (int)tile_n;
  #pragma unroll
  for (int mi = 0; mi < 8; ++mi) {
    const int seq = seq0 + wm + mi * 16 + quad * 4;
    #pragma unroll
    for (int ni = 0; ni < 2; ++ni) {
      const int d = d0 + wn + ni * 16 + l16;
      union { ushort4 u; unsigned short sh[4]; } pk;
      #pragma unroll
      for (int r = 0; r < 4; ++r)
        pk.sh[r] = __bfloat16_as_ushort(__float2bfloat16(acc[mi][ni][r]));
      *(ushort4*)(Vt + ((long long)(b * 1024 + d)) * 2048 + seq) = pk.u;
    }
  }
}

// ---------------- S = exp(Q K^T) + row-sum partials, 256x256 ----------------
__global__ __launch_bounds__(512, 2)
void gemm_s_exp(const __hip_bfloat16* __restrict__ A,
                const __hip_bfloat16* __restrict__ B,
                __hip_bfloat16* __restrict__ Cout,
                float* __restrict__ part)
{
  __shared__ __align__(16) __hip_bfloat16 As[2][256 * 64];   // 64 KB
  __shared__ __align__(16) __hip_bfloat16 Bs[2][256 * 64];   // 64 KB

  const int bz = blockIdx.z;
  A += (long long)bz * 2048 * 1024;
  B += (long long)bz * 2048 * 1024;

  const long long tile_m = (long long)blockIdx.y * 256;
  const long long tile_n = (long long)blockIdx.x * 256;

  const int tid  = threadIdx.x;
  const int wid  = tid >> 6;
  const int lane = tid & 63;
  const int srow = wid * 8 + (lane >> 3);
  const int scol = ((lane & 7) ^ (lane >> 3)) * 8;

  const __hip_bfloat16* aS = A + (tile_m + srow) * 1024 + scol;
  const __hip_bfloat16* bS = B + (tile_n + srow) * 1024 + scol;

  const int wm   = (wid >> 2) * 128;
  const int wn   = (wid & 3) * 64;
  const int quad = lane >> 4;
  const int l16  = lane & 15;
  const int sw   = l16 & 7;

  f32x4 acc[8][4];
  #pragma unroll
  for (int mi = 0; mi < 8; ++mi)
    #pragma unroll
    for (int ni = 0; ni < 4; ++ni)
      acc[mi][ni] = (f32x4){0.f, 0.f, 0.f, 0.f};

  mainloop256<4, 16, 1024>(aS, bS, &As[0][0], &Bs[0][0],
                           wid, wm, wn, l16, quad, sw, acc);

  // epilogue: exp, bf16 store, per-wave 64-col row partials (32 per row total)
  __hip_bfloat16* C = Cout + (long long)bz * 2048 * 2048;
  #pragma unroll
  for (int mi = 0; mi < 8; ++mi) {
    #pragma unroll
    for (int r = 0; r < 4; ++r) {
      const long long row = tile_m + wm + mi * 16 + quad * 4 + r;
      float ssum = 0.f;
      #pragma unroll
      for (int ni = 0; ni < 4; ++ni) {
        const float e = __expf(acc[mi][ni][r]);
        const __hip_bfloat16 h = __float2bfloat16(e);
        C[row * 2048 + tile_n + wn + ni * 16 + l16] = h;
        ssum += __bfloat162float(h);
      }
      #pragma unroll
      for (int off = 1; off < 16; off <<= 1) ssum += __shfl_xor(ssum, off, 64);
      if (l16 == 0)
        part[((long long)bz * 2048 + row) * 32 + blockIdx.x * 4 + (wid & 3)] = ssum;
    }
  }
}

// ---------------- O = (P Vt^T) / rowsum, 256x128, pipelined ----------------
__global__ __launch_bounds__(512, 2)
void gemm_pv(const __hip_bfloat16* __restrict__ A,     // expS [b][2048,2048]
             const __hip_bfloat16* __restrict__ B,     // Vt   [b][1024,2048]
             const float* __restrict__ part,           // [8192][32]
             float* __restrict__ Cout)                 // O    [b][2048,1024]
{
  __shared__ __align__(16) __hip_bfloat16 As[2][256 * 64];   // 64 KB
  __shared__ __align__(16) __hip_bfloat16 Bs[2][128 * 64];   // 32 KB
  __shared__ float rinv[256];

  const int bz = blockIdx.z;
  A += (long long)bz * 2048 * 2048;
  B += (long long)bz * 1024 * 2048;

  const long long tile_m = (long long)blockIdx.y * 256;
  const long long tile_n = (long long)blockIdx.x * 128;

  const int tid  = threadIdx.x;
  const int wid  = tid >> 6;
  const int lane = tid & 63;
  const int srow = wid * 8 + (lane >> 3);
  const int scol = ((lane & 7) ^ (lane >> 3)) * 8;

  const __hip_bfloat16* aS = A + (tile_m + srow) * 2048 + scol;
  const __hip_bfloat16* bS = B + (tile_n + srow) * 2048 + scol;

  const int wm   = (wid >> 2) * 128;
  const int wn   = (wid & 3) * 32;
  const int quad = lane >> 4;
  const int l16  = lane & 15;
  const int sw   = l16 & 7;

  f32x4 acc[8][2];
  #pragma unroll
  for (int mi = 0; mi < 8; ++mi)
    #pragma unroll
    for (int ni = 0; ni < 2; ++ni)
      acc[mi][ni] = (f32x4){0.f, 0.f, 0.f, 0.f};

  mainloop256<2, 32, 2048>(aS, bS, &As[0][0], &Bs[0][0],
                           wid, wm, wn, l16, quad, sw, acc);

  // gather this tile's 256 row-sums (32 partials each), store reciprocal
  if (tid < 256) {
    const float4* pp = (const float4*)(part + ((long long)bz * 2048 + tile_m + tid) * 32);
    float s = 0.f;
    #pragma unroll
    for (int j = 0; j < 8; ++j) {
      const float4 f = pp[j];
      s += f.x + f.y + f.z + f.w;
    }
    rinv[tid] = 1.f / s;
  }
  __syncthreads();

  float* C = Cout + (long long)bz * 2048 * 1024;
  #pragma unroll
  for (int mi = 0; mi < 8; ++mi) {
    #pragma unroll
    for (int r = 0; r < 4; ++r) {
      const int rloc = wm + mi * 16 + quad * 4 + r;
      const float inv = rinv[rloc];
      const long long row = tile_m + rloc;
      #pragma unroll
      for (int ni = 0; ni < 2; ++ni) {
        const long long col = tile_n + wn + ni * 16 + l16;
        C[row * 1024 + col] = acc[mi][ni][r] * inv;
      }
    }
  }
}

// ---------------- all casts in one dispatch ----------------
__global__ __launch_bounds__(256)
void cast_all(const float* __restrict__ x,
              const float* __restrict__ Wq, const float* __restrict__ Wk,
              const float* __restrict__ Wv,
              __hip_bfloat16* __restrict__ xb, __hip_bfloat16* __restrict__ wcat)
{
  const int bx = blockIdx.x;
  const float* src;
  __hip_bfloat16* dst;
  int i;
  if (bx < 8192) {                      // x: 2097152 float4s
    src = x; dst = xb; i = bx * 256 + threadIdx.x;
  } else {                              // weights: 262144 float4s each
    const int which = (bx - 8192) >> 10;
    src = (which == 0) ? Wq : (which == 1) ? Wk : Wv;
    dst = wcat + (long long)which * 1048576;
    i = ((bx - 8192) & 1023) * 256 + threadIdx.x;
  }
  const float4 f = ((const float4*)src)[i];
  union { ushort4 u; __hip_bfloat16 h[4]; } r;
  r.h[0] = __float2bfloat16(f.x);
  r.h[1] = __float2bfloat16(f.y);
  r.h[2] = __float2bfloat16(f.z);
  r.h[3] = __float2bfloat16(f.w);
  ((ushort4*)dst)[i] = r.u;
}

extern "C" void kernel_launch(void* const* d_in, const int* in_sizes, int n_in,
                              void* d_out, int out_size, void* d_ws, size_t ws_size,
                              hipStream_t stream)
{
  (void)in_sizes; (void)n_in; (void)out_size; (void)ws_size;

  const float* x  = (const float*)d_in[0];
  const float* Wq = (const float*)d_in[1];
  const float* Wk = (const float*)d_in[2];
  const float* Wv = (const float*)d_in[3];
  float* out = (float*)d_out;

  char* ws = (char*)d_ws;
  __hip_bfloat16* xb   = (__hip_bfloat16*)(ws);            // dead after gemm_v
  float*          part = (float*)(ws);                     // reuses xb region (1 MB)
  __hip_bfloat16* wcat = (__hip_bfloat16*)(ws + (16LL << 20));
  __hip_bfloat16* Q    = (__hip_bfloat16*)(ws + (22LL << 20));
  __hip_bfloat16* Kk   = (__hip_bfloat16*)(ws + (38LL << 20));
  __hip_bfloat16* Vt   = (__hip_bfloat16*)(ws + (54LL << 20));
  __hip_bfloat16* S    = (__hip_bfloat16*)(ws + (70LL << 20));

  cast_all<<<11264, 256, 0, stream>>>(x, Wq, Wk, Wv, xb, wcat);

  // Q,K projection: 32x8 tiles of 256^2 = 256 blocks (1 clean round)
  gemm_qk<<<256, 512, 0, stream>>>(xb, wcat, Q, Kk);

  // V projection: 32x8 tiles of 256x128 = 256 blocks; V lands transposed
  gemm_v<<<256, 512, 0, stream>>>(xb, wcat + 2097152, Vt);

  // S = exp(Q K^T), row-sum partials -> part (overwrites dead xb)
  gemm_s_exp<<<dim3(8, 8, 4), 512, 0, stream>>>(Q, Kk, S, part);

  // O = (P Vt^T) / rowsum -> fp32 d_out
  gemm_pv<<<dim3(8, 8, 4), 512, 0, stream>>>(S, Vt, part, out);
}

// Round 8
// 222.248 us; speedup vs baseline: 1.1106x; 1.0542x over previous
//
#include <hip/hip_runtime.h>
#include <hip/hip_bf16.h>
#include <stdint.h>

// ---------------------------------------------------------------------------
// Self-attention, single head, d=1024, seq=2048, batch=4, fp32 in/out.
// R15: fixes the R13/R14 register-clobber bug. In region 2 the order was
//      RD_AF(afn, ph3) BEFORE MM(afn, ph1): afn (loaded with ph1 data in
//      region 1) was overwritten with ph3 data before the ph1 MFMA consumed
//      it -> rows wm+[32..63] used A-rows wm+[96..127] -> deterministic
//      absmax 0.075 independent of fences (R13 == R14 bit-for-bit).
//      Fix (order only): RD_AF(afc,ph2); MM(afn,ph1); RD_AF(afn,ph3);
//      MM(afc,ph2); MM(afn,ph3). Load-issue still precedes the previous
//      phase's MFMAs so LDS latency hides under MFMA.
//      Everything else identical to R14: pinned vmcnt gates (SB0 +
//      "memory"), compiler-scheduled region interiors (no lgkmcnt fences),
//      2 barriers/K-tile, XCD swizzle on all four GEMMs, 256-block grids.
//      Hazards (re-audited): B reads consumed by MM ph0 before midbar; all
//      A reads consumed before endbar; no register reused before last use;
//      gate queue NI=4: B[4] A[4] B[4] -> vmcnt(4); NI=2: B[2] A[4] B[2]
//      -> vmcnt(2).
// Pipeline: cast_all | QK proj | V proj (-> Vt scatter) |
//           S = exp(QK^T) + rowsum partials | O = (P Vt^T)/rowsum
// Workspace (102 MiB): xb @ 0 (16; 1st MiB reused as part after v)
//   wcat @ 16 (6)  Q @ 22 (16)  K @ 38 (16)  Vt @ 54 (16)  S @ 70 (32)
// ---------------------------------------------------------------------------

typedef __attribute__((ext_vector_type(8))) short bf16x8;   // 8 bf16 = 4 VGPRs
typedef __attribute__((ext_vector_type(4))) float f32x4;

__device__ __forceinline__ void async_copy16(const void* g, void* l) {
  __builtin_amdgcn_global_load_lds(
      (__attribute__((address_space(1))) void*)(g),
      (__attribute__((address_space(3))) void*)(l),
      16, 0, 0);
}

// ---- 256xBN / BK=64 / 2-barrier-per-tile mainloop, compiler-scheduled ----
// NI: B-frags per wave (4 -> BN=256, 2 -> BN=128). NT: K/64. KS: row stride.
// aS/bS: per-lane staging source = Op + (tile_base + srow)*KS + scol
// As: LDS [2][256*64] bf16 (32KB/buf). Bs: LDS [2][NI*64*64] (NI*8KB/buf).
template<int NI, int NT, int KS>
__device__ __forceinline__ void mainloop256(
    const __hip_bfloat16* __restrict__ aS,
    const __hip_bfloat16* __restrict__ bS,
    __hip_bfloat16* As, __hip_bfloat16* Bs,
    const int wid, const int wm, const int wn,
    const int l16, const int quad, const int sw,
    f32x4 (&acc)[8][NI])
{
  const bf16x8* Av = (const bf16x8*)As;
  const bf16x8* Bv = (const bf16x8*)Bs;
  char* lA = (char*)As + wid * 1024;     // wave-uniform stage base
  char* lB = (char*)Bs + wid * 1024;
  bf16x8 bfr[NI][2];                     // B frags, held across the tile
  bf16x8 afc[2][2], afn[2][2];           // A frags, ping-pong across phases

#define SB0 __builtin_amdgcn_sched_barrier(0)

#define STG_A2(t) do { \
    _Pragma("unroll") \
    for (int p = 0; p < 4; ++p) \
      async_copy16(aS + ((t)*64 + (long long)p * 64 * KS), \
                   lA + ((t)&1)*32768 + p * 64 * 128); \
  } while (0)
#define STG_B2(t) do { \
    _Pragma("unroll") \
    for (int p = 0; p < NI; ++p) \
      async_copy16(bS + ((t)*64 + (long long)p * 64 * KS), \
                   lB + ((t)&1)*(NI*8192) + p * 64 * 128); \
  } while (0)

#define RD_AF(dst, t, phi) do { \
    _Pragma("unroll") \
    for (int m2 = 0; m2 < 2; ++m2) \
      _Pragma("unroll") \
      for (int kk = 0; kk < 2; ++kk) \
        dst[m2][kk] = Av[((t)&1)*2048 + (wm + ((phi)*2 + m2)*16 + l16)*8 + ((kk*4 + quad) ^ sw)]; \
  } while (0)
#define RD_BF(t, nlo, nhi) do { \
    _Pragma("unroll") \
    for (int ni = (nlo); ni < (nhi); ++ni) \
      _Pragma("unroll") \
      for (int kk = 0; kk < 2; ++kk) \
        bfr[ni][kk] = Bv[((t)&1)*(NI*512) + (wn + ni*16 + l16)*8 + ((kk*4 + quad) ^ sw)]; \
  } while (0)
#define MM(src, phi, nlo, nhi) do { \
    _Pragma("unroll") \
    for (int kk = 0; kk < 2; ++kk) \
      _Pragma("unroll") \
      for (int m2 = 0; m2 < 2; ++m2) \
        _Pragma("unroll") \
        for (int ni = (nlo); ni < (nhi); ++ni) \
          acc[(phi)*2 + m2][ni] = __builtin_amdgcn_mfma_f32_16x16x32_bf16( \
              src[m2][kk], bfr[ni][kk], acc[(phi)*2 + m2][ni], 0, 0, 0); \
  } while (0)

  // Pinned gates: SB0 keeps every staging op issued BEFORE the counted
  // wait; "memory" clobber stops memory ops crossing the asm.
#define GATEN do { SB0; \
    if constexpr (NI == 4) asm volatile("s_waitcnt vmcnt(4)" ::: "memory"); \
    else                   asm volatile("s_waitcnt vmcnt(2)" ::: "memory"); \
  } while (0)
#define GATE0 do { SB0; \
    asm volatile("s_waitcnt vmcnt(0)" ::: "memory"); } while (0)
#define GNONE (void)0

  // One K-tile t. STG0 = A(t+1) staging, STG1 = B(t+2) staging,
  // GATE = vmcnt wait covering A(t+1)+B(t+1) before the end barrier.
  // Region interiors compiler-scheduled (counted lgkm waits auto-inserted).
  // Register dataflow (R15 fix): afc: ph0 -> consumed -> ph2 -> consumed;
  // afn: ph1 -> consumed -> ph3 -> consumed. No clobber before last use.
#define TILE(t, STG0_STMT, STG1_STMT, GATE_STMT) do { \
    /* Region 1: all B reads + A ph0/ph1 reads + A-restage + MFMA ph0 */ \
    RD_BF(t, 0, NI); \
    RD_AF(afc, t, 0); \
    RD_AF(afn, t, 1); \
    STG0_STMT; \
    __builtin_amdgcn_s_setprio(1); MM(afc, 0, 0, NI); __builtin_amdgcn_s_setprio(0); \
    SB0; \
    __builtin_amdgcn_s_barrier();   /* all B-buf(t) reads drained chip-wide */ \
    /* Region 2: B(t+2) restage + MFMA ph1-ph3 with interleaved A reads */ \
    STG1_STMT; \
    RD_AF(afc, t, 2); \
    __builtin_amdgcn_s_setprio(1); \
    MM(afn, 1, 0, NI); \
    __builtin_amdgcn_s_setprio(0); \
    RD_AF(afn, t, 3); \
    __builtin_amdgcn_s_setprio(1); \
    MM(afc, 2, 0, NI); \
    MM(afn, 3, 0, NI); \
    __builtin_amdgcn_s_setprio(0); \
    GATE_STMT; \
    SB0; \
    __builtin_amdgcn_s_barrier(); \
  } while (0)

  // prologue: B(0), A(0), B(1); keep B(1)'s lines outstanding
  STG_B2(0); STG_A2(0); STG_B2(1);
  GATEN;
  __builtin_amdgcn_s_barrier();

  #pragma unroll 1
  for (int i = 0; i < NT / 2 - 1; ++i) {
    const int ta = 2 * i, tb = 2 * i + 1;
    TILE(ta, STG_A2(tb),     STG_B2(ta + 2), GATEN);
    TILE(tb, STG_A2(ta + 2), STG_B2(tb + 2), GATEN);
  }
  // peeled: tile NT-2 stages only A(NT-1); tile NT-1 stages nothing.
  TILE(NT - 2, STG_A2(NT - 1), GNONE, GATE0);
  TILE(NT - 1, GNONE,          GNONE, GNONE);

#undef TILE
#undef GATEN
#undef GATE0
#undef GNONE
#undef MM
#undef RD_BF
#undef RD_AF
#undef STG_A2
#undef STG_B2
#undef SB0
}

// ---------------- Q,K projection, 256x256, grid 256 ----------------
// A = xb [8192,1024], B = wcat rows 0..2047 (Wq | Wk)
__global__ __launch_bounds__(512, 2)
void gemm_qk(const __hip_bfloat16* __restrict__ A,
             const __hip_bfloat16* __restrict__ B,
             __hip_bfloat16* __restrict__ Q,
             __hip_bfloat16* __restrict__ Kk)
{
  __shared__ __align__(16) __hip_bfloat16 As[2][256 * 64];   // 64 KB
  __shared__ __align__(16) __hip_bfloat16 Bs[2][256 * 64];   // 64 KB

  // XCD-chunked bijective swizzle: 256 = 8 XCD * 32; same-XCD blocks span
  // 4 consecutive tile_m panels x 8 tile_n (A-panel reuse in per-XCD L2).
  const int bid = blockIdx.x;
  const int s   = (bid & 7) * 32 + (bid >> 3);
  const long long tile_m = (long long)(s >> 3) * 256;
  const long long tile_n = (long long)(s & 7) * 256;

  const int tid  = threadIdx.x;
  const int wid  = tid >> 6;
  const int lane = tid & 63;
  const int srow = wid * 8 + (lane >> 3);
  const int scol = ((lane & 7) ^ (lane >> 3)) * 8;   // swizzled source chunk

  const __hip_bfloat16* aS = A + (tile_m + srow) * 1024 + scol;
  const __hip_bfloat16* bS = B + (tile_n + srow) * 1024 + scol;

  const int wm   = (wid >> 2) * 128;
  const int wn   = (wid & 3) * 64;
  const int quad = lane >> 4;
  const int l16  = lane & 15;
  const int sw   = l16 & 7;

  f32x4 acc[8][4];
  #pragma unroll
  for (int mi = 0; mi < 8; ++mi)
    #pragma unroll
    for (int ni = 0; ni < 4; ++ni)
      acc[mi][ni] = (f32x4){0.f, 0.f, 0.f, 0.f};

  mainloop256<4, 16, 1024>(aS, bS, &As[0][0], &Bs[0][0],
                           wid, wm, wn, l16, quad, sw, acc);

  // C/D layout (m89/m91): col = l16, row = quad*4 + r
  const int mat = (int)(tile_n >> 10);
  __hip_bfloat16* outp = (mat == 0) ? Q : Kk;
  const float scale = (mat == 0) ? 0.03125f : 1.0f;   // 1/sqrt(1024) in Q
  const int coln0 = (int)(tile_n & 1023);
  #pragma unroll
  for (int mi = 0; mi < 8; ++mi) {
    #pragma unroll
    for (int r = 0; r < 4; ++r) {
      const long long row = tile_m + wm + mi * 16 + quad * 4 + r;
      #pragma unroll
      for (int ni = 0; ni < 4; ++ni) {
        const int col = coln0 + wn + ni * 16 + l16;
        outp[row * 1024 + col] = __float2bfloat16(acc[mi][ni][r] * scale);
      }
    }
  }
}

// ---------------- V projection, 256x128, grid 256 ----------------
// A = xb [8192,1024], B = Wv rows.  V -> Vt [4][1024][2048] via 8B scatter.
__global__ __launch_bounds__(512, 2)
void gemm_v(const __hip_bfloat16* __restrict__ A,
            const __hip_bfloat16* __restrict__ B,
            __hip_bfloat16* __restrict__ Vt)
{
  __shared__ __align__(16) __hip_bfloat16 As[2][256 * 64];   // 64 KB
  __shared__ __align__(16) __hip_bfloat16 Bs[2][128 * 64];   // 32 KB

  const int bid = blockIdx.x;
  const int s   = (bid & 7) * 32 + (bid >> 3);
  const long long tile_m = (long long)(s >> 3) * 256;
  const long long tile_n = (long long)(s & 7) * 128;

  const int tid  = threadIdx.x;
  const int wid  = tid >> 6;
  const int lane = tid & 63;
  const int srow = wid * 8 + (lane >> 3);
  const int scol = ((lane & 7) ^ (lane >> 3)) * 8;

  const __hip_bfloat16* aS = A + (tile_m + srow) * 1024 + scol;
  const __hip_bfloat16* bS = B + (tile_n + srow) * 1024 + scol;

  const int wm   = (wid >> 2) * 128;
  const int wn   = (wid & 3) * 32;
  const int quad = lane >> 4;
  const int l16  = lane & 15;
  const int sw   = l16 & 7;

  f32x4 acc[8][2];
  #pragma unroll
  for (int mi = 0; mi < 8; ++mi)
    #pragma unroll
    for (int ni = 0; ni < 2; ++ni)
      acc[mi][ni] = (f32x4){0.f, 0.f, 0.f, 0.f};

  mainloop256<2, 16, 1024>(aS, bS, &As[0][0], &Bs[0][0],
                           wid, wm, wn, l16, quad, sw, acc);

  // V: lane's 4 r-values are seq-consecutive -> one 8B store per (mi,ni).
  const int b    = (int)(tile_m >> 11);
  const int seq0 = (int)(tile_m & 2047);
  const int d0   = (int)tile_n;
  #pragma unroll
  for (int mi = 0; mi < 8; ++mi) {
    const int seq = seq0 + wm + mi * 16 + quad * 4;
    #pragma unroll
    for (int ni = 0; ni < 2; ++ni) {
      const int d = d0 + wn + ni * 16 + l16;
      union { ushort4 u; unsigned short sh[4]; } pk;
      #pragma unroll
      for (int r = 0; r < 4; ++r)
        pk.sh[r] = __bfloat16_as_ushort(__float2bfloat16(acc[mi][ni][r]));
      *(ushort4*)(Vt + ((long long)(b * 1024 + d)) * 2048 + seq) = pk.u;
    }
  }
}

// ---------------- S = exp(Q K^T) + row-sum partials, 256x256 ----------------
__global__ __launch_bounds__(512, 2)
void gemm_s_exp(const __hip_bfloat16* __restrict__ A,
                const __hip_bfloat16* __restrict__ B,
                __hip_bfloat16* __restrict__ Cout,
                float* __restrict__ part)
{
  __shared__ __align__(16) __hip_bfloat16 As[2][256 * 64];   // 64 KB
  __shared__ __align__(16) __hip_bfloat16 Bs[2][256 * 64];   // 64 KB

  // XCD swizzle: flat id -> (xcd, r); each XCD owns one batch-half:
  // 4 consecutive tile_m x all 8 tile_n (footprint ~6 MB in per-XCD L2).
  const int u   = blockIdx.x + (blockIdx.y << 3) + (blockIdx.z << 6);
  const int xcd = u & 7;
  const int rr  = u >> 3;                 // 0..31
  const int bz  = xcd >> 1;               // 2 XCDs per batch
  const int tmi = ((xcd & 1) << 2) + (rr >> 3);
  const int tni = rr & 7;

  A += (long long)bz * 2048 * 1024;
  B += (long long)bz * 2048 * 1024;

  const long long tile_m = (long long)tmi * 256;
  const long long tile_n = (long long)tni * 256;

  const int tid  = threadIdx.x;
  const int wid  = tid >> 6;
  const int lane = tid & 63;
  const int srow = wid * 8 + (lane >> 3);
  const int scol = ((lane & 7) ^ (lane >> 3)) * 8;

  const __hip_bfloat16* aS = A + (tile_m + srow) * 1024 + scol;
  const __hip_bfloat16* bS = B + (tile_n + srow) * 1024 + scol;

  const int wm   = (wid >> 2) * 128;
  const int wn   = (wid & 3) * 64;
  const int quad = lane >> 4;
  const int l16  = lane & 15;
  const int sw   = l16 & 7;

  f32x4 acc[8][4];
  #pragma unroll
  for (int mi = 0; mi < 8; ++mi)
    #pragma unroll
    for (int ni = 0; ni < 4; ++ni)
      acc[mi][ni] = (f32x4){0.f, 0.f, 0.f, 0.f};

  mainloop256<4, 16, 1024>(aS, bS, &As[0][0], &Bs[0][0],
                           wid, wm, wn, l16, quad, sw, acc);

  // epilogue: exp, bf16 store, per-wave 64-col row partials (32 per row total)
  __hip_bfloat16* C = Cout + (long long)bz * 2048 * 2048;
  #pragma unroll
  for (int mi = 0; mi < 8; ++mi) {
    #pragma unroll
    for (int r = 0; r < 4; ++r) {
      const long long row = tile_m + wm + mi * 16 + quad * 4 + r;
      float ssum = 0.f;
      #pragma unroll
      for (int ni = 0; ni < 4; ++ni) {
        const float e = __expf(acc[mi][ni][r]);
        const __hip_bfloat16 h = __float2bfloat16(e);
        C[row * 2048 + tile_n + wn + ni * 16 + l16] = h;
        ssum += __bfloat162float(h);
      }
      #pragma unroll
      for (int off = 1; off < 16; off <<= 1) ssum += __shfl_xor(ssum, off, 64);
      if (l16 == 0)
        part[((long long)bz * 2048 + row) * 32 + tni * 4 + (wid & 3)] = ssum;
    }
  }
}

// ---------------- O = (P Vt^T) / rowsum, 256x128, pipelined ----------------
__global__ __launch_bounds__(512, 2)
void gemm_pv(const __hip_bfloat16* __restrict__ A,     // expS [b][2048,2048]
             const __hip_bfloat16* __restrict__ B,     // Vt   [b][1024,2048]
             const float* __restrict__ part,           // [8192][32]
             float* __restrict__ Cout)                 // O    [b][2048,1024]
{
  __shared__ __align__(16) __hip_bfloat16 As[2][256 * 64];   // 64 KB
  __shared__ __align__(16) __hip_bfloat16 Bs[2][128 * 64];   // 32 KB
  __shared__ float rinv[256];

  // XCD swizzle: each XCD owns 4 tile_m x 8 tile_n of one batch
  // (A 4x1MB streams with 8-way sharing, B 8x0.5MB resident).
  const int u   = blockIdx.x + (blockIdx.y << 3) + (blockIdx.z << 6);
  const int xcd = u & 7;
  const int rr  = u >> 3;
  const int bz  = xcd >> 1;
  const int tmi = ((xcd & 1) << 2) + (rr >> 3);
  const int tni = rr & 7;

  A += (long long)bz * 2048 * 2048;
  B += (long long)bz * 1024 * 2048;

  const long long tile_m = (long long)tmi * 256;
  const long long tile_n = (long long)tni * 128;

  const int tid  = threadIdx.x;
  const int wid  = tid >> 6;
  const int lane = tid & 63;
  const int srow = wid * 8 + (lane >> 3);
  const int scol = ((lane & 7) ^ (lane >> 3)) * 8;

  const __hip_bfloat16* aS = A + (tile_m + srow) * 2048 + scol;
  const __hip_bfloat16* bS = B + (tile_n + srow) * 2048 + scol;

  const int wm   = (wid >> 2) * 128;
  const int wn   = (wid & 3) * 32;
  const int quad = lane >> 4;
  const int l16  = lane & 15;
  const int sw   = l16 & 7;

  f32x4 acc[8][2];
  #pragma unroll
  for (int mi = 0; mi < 8; ++mi)
    #pragma unroll
    for (int ni = 0; ni < 2; ++ni)
      acc[mi][ni] = (f32x4){0.f, 0.f, 0.f, 0.f};

  mainloop256<2, 32, 2048>(aS, bS, &As[0][0], &Bs[0][0],
                           wid, wm, wn, l16, quad, sw, acc);

  // gather this tile's 256 row-sums (32 partials each), store reciprocal
  if (tid < 256) {
    const float4* pp = (const float4*)(part + ((long long)bz * 2048 + tile_m + tid) * 32);
    float s = 0.f;
    #pragma unroll
    for (int j = 0; j < 8; ++j) {
      const float4 f = pp[j];
      s += f.x + f.y + f.z + f.w;
    }
    rinv[tid] = 1.f / s;
  }
  __syncthreads();

  float* C = Cout + (long long)bz * 2048 * 1024;
  #pragma unroll
  for (int mi = 0; mi < 8; ++mi) {
    #pragma unroll
    for (int r = 0; r < 4; ++r) {
      const int rloc = wm + mi * 16 + quad * 4 + r;
      const float inv = rinv[rloc];
      const long long row = tile_m + rloc;
      #pragma unroll
      for (int ni = 0; ni < 2; ++ni) {
        const long long col = tile_n + wn + ni * 16 + l16;
        C[row * 1024 + col] = acc[mi][ni][r] * inv;
      }
    }
  }
}

// ---------------- all casts in one dispatch ----------------
__global__ __launch_bounds__(256)
void cast_all(const float* __restrict__ x,
              const float* __restrict__ Wq, const float* __restrict__ Wk,
              const float* __restrict__ Wv,
              __hip_bfloat16* __restrict__ xb, __hip_bfloat16* __restrict__ wcat)
{
  const int bx = blockIdx.x;
  const float* src;
  __hip_bfloat16* dst;
  int i;
  if (bx < 8192) {                      // x: 2097152 float4s
    src = x; dst = xb; i = bx * 256 + threadIdx.x;
  } else {                              // weights: 262144 float4s each
    const int which = (bx - 8192) >> 10;
    src = (which == 0) ? Wq : (which == 1) ? Wk : Wv;
    dst = wcat + (long long)which * 1048576;
    i = ((bx - 8192) & 1023) * 256 + threadIdx.x;
  }
  const float4 f = ((const float4*)src)[i];
  union { ushort4 u; __hip_bfloat16 h[4]; } r;
  r.h[0] = __float2bfloat16(f.x);
  r.h[1] = __float2bfloat16(f.y);
  r.h[2] = __float2bfloat16(f.z);
  r.h[3] = __float2bfloat16(f.w);
  ((ushort4*)dst)[i] = r.u;
}

extern "C" void kernel_launch(void* const* d_in, const int* in_sizes, int n_in,
                              void* d_out, int out_size, void* d_ws, size_t ws_size,
                              hipStream_t stream)
{
  (void)in_sizes; (void)n_in; (void)out_size; (void)ws_size;

  const float* x  = (const float*)d_in[0];
  const float* Wq = (const float*)d_in[1];
  const float* Wk = (const float*)d_in[2];
  const float* Wv = (const float*)d_in[3];
  float* out = (float*)d_out;

  char* ws = (char*)d_ws;
  __hip_bfloat16* xb   = (__hip_bfloat16*)(ws);            // dead after gemm_v
  float*          part = (float*)(ws);                     // reuses xb region (1 MB)
  __hip_bfloat16* wcat = (__hip_bfloat16*)(ws + (16LL << 20));
  __hip_bfloat16* Q    = (__hip_bfloat16*)(ws + (22LL << 20));
  __hip_bfloat16* Kk   = (__hip_bfloat16*)(ws + (38LL << 20));
  __hip_bfloat16* Vt   = (__hip_bfloat16*)(ws + (54LL << 20));
  __hip_bfloat16* S    = (__hip_bfloat16*)(ws + (70LL << 20));

  cast_all<<<11264, 256, 0, stream>>>(x, Wq, Wk, Wv, xb, wcat);

  // Q,K projection: 32x8 tiles of 256^2 = 256 blocks (1 clean round)
  gemm_qk<<<256, 512, 0, stream>>>(xb, wcat, Q, Kk);

  // V projection: 32x8 tiles of 256x128 = 256 blocks; V lands transposed
  gemm_v<<<256, 512, 0, stream>>>(xb, wcat + 2097152, Vt);

  // S = exp(Q K^T), row-sum partials -> part (overwrites dead xb)
  gemm_s_exp<<<dim3(8, 8, 4), 512, 0, stream>>>(Q, Kk, S, part);

  // O = (P Vt^T) / rowsum -> fp32 d_out
  gemm_pv<<<dim3(8, 8, 4), 512, 0, stream>>>(S, Vt, part, out);
}

// Round 9
// 220.883 us; speedup vs baseline: 1.1174x; 1.0062x over previous
//
#include <hip/hip_runtime.h>
#include <hip/hip_bf16.h>
#include <stdint.h>

// ---------------------------------------------------------------------------
// Self-attention, single head, d=1024, seq=2048, batch=4, fp32 in/out.
// R16: single-barrier mainloop. R15 counters: pv MfmaUtil 29%, FETCH ideal,
//      timing == serial sum of LDS (~2100 cyc) + MFMA (~1240 cyc/SIMD) per
//      K-tile -> pipes don't overlap because the mid-barrier resyncs all 8
//      waves twice per tile (lockstep bursts). The mid-barrier existed only
//      for B(t+2) restaging into the live read buffer. Fix: stage A(t+1)
//      AND B(t+1) during tile t -> both land in buf (t+1)&1 (never the
//      read buffer) -> mid-barrier deleted, ONE barrier per K-tile, gate =
//      vmcnt(0) (nearly free: stages issued a full tile ~2500 cyc before
//      the gate >> 900 cyc HBM latency). Waves skew across the whole tile:
//      LDS pipe streams while SIMDs compute.
//      Hazards (audited): A/B(t+1) writes target buf^1 whose last reads
//      completed before tile t-1's end barrier (stage issued after it);
//      vmcnt(0)+barrier publishes stages before tile t+1 reads; R15
//      register dataflow unchanged (afc: ph0->ph2, afn: ph1->ph3).
//      Everything else identical to R15 (XCD swizzles, epilogues, grids).
// Pipeline: cast_all | QK proj | V proj (-> Vt scatter) |
//           S = exp(QK^T) + rowsum partials | O = (P Vt^T)/rowsum
// Workspace (102 MiB): xb @ 0 (16; 1st MiB reused as part after v)
//   wcat @ 16 (6)  Q @ 22 (16)  K @ 38 (16)  Vt @ 54 (16)  S @ 70 (32)
// ---------------------------------------------------------------------------

typedef __attribute__((ext_vector_type(8))) short bf16x8;   // 8 bf16 = 4 VGPRs
typedef __attribute__((ext_vector_type(4))) float f32x4;

__device__ __forceinline__ void async_copy16(const void* g, void* l) {
  __builtin_amdgcn_global_load_lds(
      (__attribute__((address_space(1))) void*)(g),
      (__attribute__((address_space(3))) void*)(l),
      16, 0, 0);
}

// ---- 256xBN / BK=64 / 1-barrier-per-tile mainloop, compiler-scheduled ----
// NI: B-frags per wave (4 -> BN=256, 2 -> BN=128). NT: K/64. KS: row stride.
// aS/bS: per-lane staging source = Op + (tile_base + srow)*KS + scol
// As: LDS [2][256*64] bf16 (32KB/buf). Bs: LDS [2][NI*64*64] (NI*8KB/buf).
template<int NI, int NT, int KS>
__device__ __forceinline__ void mainloop256(
    const __hip_bfloat16* __restrict__ aS,
    const __hip_bfloat16* __restrict__ bS,
    __hip_bfloat16* As, __hip_bfloat16* Bs,
    const int wid, const int wm, const int wn,
    const int l16, const int quad, const int sw,
    f32x4 (&acc)[8][NI])
{
  const bf16x8* Av = (const bf16x8*)As;
  const bf16x8* Bv = (const bf16x8*)Bs;
  char* lA = (char*)As + wid * 1024;     // wave-uniform stage base
  char* lB = (char*)Bs + wid * 1024;
  bf16x8 bfr[NI][2];                     // B frags, held across the tile
  bf16x8 afc[2][2], afn[2][2];           // A frags, ping-pong across phases

#define SB0 __builtin_amdgcn_sched_barrier(0)

#define STG_A2(t) do { \
    _Pragma("unroll") \
    for (int p = 0; p < 4; ++p) \
      async_copy16(aS + ((t)*64 + (long long)p * 64 * KS), \
                   lA + ((t)&1)*32768 + p * 64 * 128); \
  } while (0)
#define STG_B2(t) do { \
    _Pragma("unroll") \
    for (int p = 0; p < NI; ++p) \
      async_copy16(bS + ((t)*64 + (long long)p * 64 * KS), \
                   lB + ((t)&1)*(NI*8192) + p * 64 * 128); \
  } while (0)

#define RD_AF(dst, t, phi) do { \
    _Pragma("unroll") \
    for (int m2 = 0; m2 < 2; ++m2) \
      _Pragma("unroll") \
      for (int kk = 0; kk < 2; ++kk) \
        dst[m2][kk] = Av[((t)&1)*2048 + (wm + ((phi)*2 + m2)*16 + l16)*8 + ((kk*4 + quad) ^ sw)]; \
  } while (0)
#define RD_BF(t, nlo, nhi) do { \
    _Pragma("unroll") \
    for (int ni = (nlo); ni < (nhi); ++ni) \
      _Pragma("unroll") \
      for (int kk = 0; kk < 2; ++kk) \
        bfr[ni][kk] = Bv[((t)&1)*(NI*512) + (wn + ni*16 + l16)*8 + ((kk*4 + quad) ^ sw)]; \
  } while (0)
#define MM(src, phi, nlo, nhi) do { \
    _Pragma("unroll") \
    for (int kk = 0; kk < 2; ++kk) \
      _Pragma("unroll") \
      for (int m2 = 0; m2 < 2; ++m2) \
        _Pragma("unroll") \
        for (int ni = (nlo); ni < (nhi); ++ni) \
          acc[(phi)*2 + m2][ni] = __builtin_amdgcn_mfma_f32_16x16x32_bf16( \
              src[m2][kk], bfr[ni][kk], acc[(phi)*2 + m2][ni], 0, 0, 0); \
  } while (0)

  // Pinned gate: SB0 keeps every staging op issued BEFORE the counted
  // wait; "memory" clobber stops memory ops crossing the asm.
#define GATE0 do { SB0; \
    asm volatile("s_waitcnt vmcnt(0)" ::: "memory"); } while (0)
#define GNONE (void)0

  // One K-tile t. STG_STMT stages A(t+1)+B(t+1) into buf (t+1)&1 right
  // after the boundary reads (max issue-to-gate distance). One barrier.
  // Register dataflow: afc: ph0 -> consumed -> ph2 -> consumed;
  // afn: ph1 -> consumed -> ph3 -> consumed. No clobber before last use.
#define TILE(t, STG_STMT, GATE_STMT) do { \
    RD_BF(t, 0, NI); \
    RD_AF(afc, t, 0); \
    RD_AF(afn, t, 1); \
    STG_STMT; \
    __builtin_amdgcn_s_setprio(1); MM(afc, 0, 0, NI); __builtin_amdgcn_s_setprio(0); \
    RD_AF(afc, t, 2); \
    __builtin_amdgcn_s_setprio(1); \
    MM(afn, 1, 0, NI); \
    __builtin_amdgcn_s_setprio(0); \
    RD_AF(afn, t, 3); \
    __builtin_amdgcn_s_setprio(1); \
    MM(afc, 2, 0, NI); \
    MM(afn, 3, 0, NI); \
    __builtin_amdgcn_s_setprio(0); \
    GATE_STMT; \
    SB0; \
    __builtin_amdgcn_s_barrier(); \
  } while (0)

  // prologue: stage tile 0 only; drain; barrier.
  STG_B2(0); STG_A2(0);
  GATE0;
  __builtin_amdgcn_s_barrier();

  // steady: tile t stages tile t+1 (A and B), gate vmcnt(0), 1 barrier.
  #pragma unroll 1
  for (int i = 0; i < NT / 2 - 1; ++i) {
    const int ta = 2 * i, tb = 2 * i + 1;
    TILE(ta, { STG_A2(ta + 1); STG_B2(ta + 1); }, GATE0);
    TILE(tb, { STG_A2(tb + 1); STG_B2(tb + 1); }, GATE0);
  }
  // peeled: tile NT-2 stages tile NT-1; tile NT-1 stages nothing.
  TILE(NT - 2, { STG_A2(NT - 1); STG_B2(NT - 1); }, GATE0);
  TILE(NT - 1, GNONE, GNONE);

#undef TILE
#undef GATE0
#undef GNONE
#undef MM
#undef RD_BF
#undef RD_AF
#undef STG_A2
#undef STG_B2
#undef SB0
}

// ---------------- Q,K projection, 256x256, grid 256 ----------------
// A = xb [8192,1024], B = wcat rows 0..2047 (Wq | Wk)
__global__ __launch_bounds__(512, 2)
void gemm_qk(const __hip_bfloat16* __restrict__ A,
             const __hip_bfloat16* __restrict__ B,
             __hip_bfloat16* __restrict__ Q,
             __hip_bfloat16* __restrict__ Kk)
{
  __shared__ __align__(16) __hip_bfloat16 As[2][256 * 64];   // 64 KB
  __shared__ __align__(16) __hip_bfloat16 Bs[2][256 * 64];   // 64 KB

  // XCD-chunked bijective swizzle: 256 = 8 XCD * 32; same-XCD blocks span
  // 4 consecutive tile_m panels x 8 tile_n (A-panel reuse in per-XCD L2).
  const int bid = blockIdx.x;
  const int s   = (bid & 7) * 32 + (bid >> 3);
  const long long tile_m = (long long)(s >> 3) * 256;
  const long long tile_n = (long long)(s & 7) * 256;

  const int tid  = threadIdx.x;
  const int wid  = tid >> 6;
  const int lane = tid & 63;
  const int srow = wid * 8 + (lane >> 3);
  const int scol = ((lane & 7) ^ (lane >> 3)) * 8;   // swizzled source chunk

  const __hip_bfloat16* aS = A + (tile_m + srow) * 1024 + scol;
  const __hip_bfloat16* bS = B + (tile_n + srow) * 1024 + scol;

  const int wm   = (wid >> 2) * 128;
  const int wn   = (wid & 3) * 64;
  const int quad = lane >> 4;
  const int l16  = lane & 15;
  const int sw   = l16 & 7;

  f32x4 acc[8][4];
  #pragma unroll
  for (int mi = 0; mi < 8; ++mi)
    #pragma unroll
    for (int ni = 0; ni < 4; ++ni)
      acc[mi][ni] = (f32x4){0.f, 0.f, 0.f, 0.f};

  mainloop256<4, 16, 1024>(aS, bS, &As[0][0], &Bs[0][0],
                           wid, wm, wn, l16, quad, sw, acc);

  // C/D layout (m89/m91): col = l16, row = quad*4 + r
  const int mat = (int)(tile_n >> 10);
  __hip_bfloat16* outp = (mat == 0) ? Q : Kk;
  const float scale = (mat == 0) ? 0.03125f : 1.0f;   // 1/sqrt(1024) in Q
  const int coln0 = (int)(tile_n & 1023);
  #pragma unroll
  for (int mi = 0; mi < 8; ++mi) {
    #pragma unroll
    for (int r = 0; r < 4; ++r) {
      const long long row = tile_m + wm + mi * 16 + quad * 4 + r;
      #pragma unroll
      for (int ni = 0; ni < 4; ++ni) {
        const int col = coln0 + wn + ni * 16 + l16;
        outp[row * 1024 + col] = __float2bfloat16(acc[mi][ni][r] * scale);
      }
    }
  }
}

// ---------------- V projection, 256x128, grid 256 ----------------
// A = xb [8192,1024], B = Wv rows.  V -> Vt [4][1024][2048] via 8B scatter.
__global__ __launch_bounds__(512, 2)
void gemm_v(const __hip_bfloat16* __restrict__ A,
            const __hip_bfloat16* __restrict__ B,
            __hip_bfloat16* __restrict__ Vt)
{
  __shared__ __align__(16) __hip_bfloat16 As[2][256 * 64];   // 64 KB
  __shared__ __align__(16) __hip_bfloat16 Bs[2][128 * 64];   // 32 KB

  const int bid = blockIdx.x;
  const int s   = (bid & 7) * 32 + (bid >> 3);
  const long long tile_m = (long long)(s >> 3) * 256;
  const long long tile_n = (long long)(s & 7) * 128;

  const int tid  = threadIdx.x;
  const int wid  = tid >> 6;
  const int lane = tid & 63;
  const int srow = wid * 8 + (lane >> 3);
  const int scol = ((lane & 7) ^ (lane >> 3)) * 8;

  const __hip_bfloat16* aS = A + (tile_m + srow) * 1024 + scol;
  const __hip_bfloat16* bS = B + (tile_n + srow) * 1024 + scol;

  const int wm   = (wid >> 2) * 128;
  const int wn   = (wid & 3) * 32;
  const int quad = lane >> 4;
  const int l16  = lane & 15;
  const int sw   = l16 & 7;

  f32x4 acc[8][2];
  #pragma unroll
  for (int mi = 0; mi < 8; ++mi)
    #pragma unroll
    for (int ni = 0; ni < 2; ++ni)
      acc[mi][ni] = (f32x4){0.f, 0.f, 0.f, 0.f};

  mainloop256<2, 16, 1024>(aS, bS, &As[0][0], &Bs[0][0],
                           wid, wm, wn, l16, quad, sw, acc);

  // V: lane's 4 r-values are seq-consecutive -> one 8B store per (mi,ni).
  const int b    = (int)(tile_m >> 11);
  const int seq0 = (int)(tile_m & 2047);
  const int d0   = (int)tile_n;
  #pragma unroll
  for (int mi = 0; mi < 8; ++mi) {
    const int seq = seq0 + wm + mi * 16 + quad * 4;
    #pragma unroll
    for (int ni = 0; ni < 2; ++ni) {
      const int d = d0 + wn + ni * 16 + l16;
      union { ushort4 u; unsigned short sh[4]; } pk;
      #pragma unroll
      for (int r = 0; r < 4; ++r)
        pk.sh[r] = __bfloat16_as_ushort(__float2bfloat16(acc[mi][ni][r]));
      *(ushort4*)(Vt + ((long long)(b * 1024 + d)) * 2048 + seq) = pk.u;
    }
  }
}

// ---------------- S = exp(Q K^T) + row-sum partials, 256x256 ----------------
__global__ __launch_bounds__(512, 2)
void gemm_s_exp(const __hip_bfloat16* __restrict__ A,
                const __hip_bfloat16* __restrict__ B,
                __hip_bfloat16* __restrict__ Cout,
                float* __restrict__ part)
{
  __shared__ __align__(16) __hip_bfloat16 As[2][256 * 64];   // 64 KB
  __shared__ __align__(16) __hip_bfloat16 Bs[2][256 * 64];   // 64 KB

  // XCD swizzle: flat id -> (xcd, r); each XCD owns one batch-half:
  // 4 consecutive tile_m x all 8 tile_n (footprint ~6 MB in per-XCD L2).
  const int u   = blockIdx.x + (blockIdx.y << 3) + (blockIdx.z << 6);
  const int xcd = u & 7;
  const int rr  = u >> 3;                 // 0..31
  const int bz  = xcd >> 1;               // 2 XCDs per batch
  const int tmi = ((xcd & 1) << 2) + (rr >> 3);
  const int tni = rr & 7;

  A += (long long)bz * 2048 * 1024;
  B += (long long)bz * 2048 * 1024;

  const long long tile_m = (long long)tmi * 256;
  const long long tile_n = (long long)tni * 256;

  const int tid  = threadIdx.x;
  const int wid  = tid >> 6;
  const int lane = tid & 63;
  const int srow = wid * 8 + (lane >> 3);
  const int scol = ((lane & 7) ^ (lane >> 3)) * 8;

  const __hip_bfloat16* aS = A + (tile_m + srow) * 1024 + scol;
  const __hip_bfloat16* bS = B + (tile_n + srow) * 1024 + scol;

  const int wm   = (wid >> 2) * 128;
  const int wn   = (wid & 3) * 64;
  const int quad = lane >> 4;
  const int l16  = lane & 15;
  const int sw   = l16 & 7;

  f32x4 acc[8][4];
  #pragma unroll
  for (int mi = 0; mi < 8; ++mi)
    #pragma unroll
    for (int ni = 0; ni < 4; ++ni)
      acc[mi][ni] = (f32x4){0.f, 0.f, 0.f, 0.f};

  mainloop256<4, 16, 1024>(aS, bS, &As[0][0], &Bs[0][0],
                           wid, wm, wn, l16, quad, sw, acc);

  // epilogue: exp, bf16 store, per-wave 64-col row partials (32 per row total)
  __hip_bfloat16* C = Cout + (long long)bz * 2048 * 2048;
  #pragma unroll
  for (int mi = 0; mi < 8; ++mi) {
    #pragma unroll
    for (int r = 0; r < 4; ++r) {
      const long long row = tile_m + wm + mi * 16 + quad * 4 + r;
      float ssum = 0.f;
      #pragma unroll
      for (int ni = 0; ni < 4; ++ni) {
        const float e = __expf(acc[mi][ni][r]);
        const __hip_bfloat16 h = __float2bfloat16(e);
        C[row * 2048 + tile_n + wn + ni * 16 + l16] = h;
        ssum += __bfloat162float(h);
      }
      #pragma unroll
      for (int off = 1; off < 16; off <<= 1) ssum += __shfl_xor(ssum, off, 64);
      if (l16 == 0)
        part[((long long)bz * 2048 + row) * 32 + tni * 4 + (wid & 3)] = ssum;
    }
  }
}

// ---------------- O = (P Vt^T) / rowsum, 256x128, pipelined ----------------
__global__ __launch_bounds__(512, 2)
void gemm_pv(const __hip_bfloat16* __restrict__ A,     // expS [b][2048,2048]
             const __hip_bfloat16* __restrict__ B,     // Vt   [b][1024,2048]
             const float* __restrict__ part,           // [8192][32]
             float* __restrict__ Cout)                 // O    [b][2048,1024]
{
  __shared__ __align__(16) __hip_bfloat16 As[2][256 * 64];   // 64 KB
  __shared__ __align__(16) __hip_bfloat16 Bs[2][128 * 64];   // 32 KB
  __shared__ float rinv[256];

  // XCD swizzle: each XCD owns 4 tile_m x 8 tile_n of one batch
  // (A 4x1MB streams with 8-way sharing, B 8x0.5MB resident).
  const int u   = blockIdx.x + (blockIdx.y << 3) + (blockIdx.z << 6);
  const int xcd = u & 7;
  const int rr  = u >> 3;
  const int bz  = xcd >> 1;
  const int tmi = ((xcd & 1) << 2) + (rr >> 3);
  const int tni = rr & 7;

  A += (long long)bz * 2048 * 2048;
  B += (long long)bz * 1024 * 2048;

  const long long tile_m = (long long)tmi * 256;
  const long long tile_n = (long long)tni * 128;

  const int tid  = threadIdx.x;
  const int wid  = tid >> 6;
  const int lane = tid & 63;
  const int srow = wid * 8 + (lane >> 3);
  const int scol = ((lane & 7) ^ (lane >> 3)) * 8;

  const __hip_bfloat16* aS = A + (tile_m + srow) * 2048 + scol;
  const __hip_bfloat16* bS = B + (tile_n + srow) * 2048 + scol;

  const int wm   = (wid >> 2) * 128;
  const int wn   = (wid & 3) * 32;
  const int quad = lane >> 4;
  const int l16  = lane & 15;
  const int sw   = l16 & 7;

  f32x4 acc[8][2];
  #pragma unroll
  for (int mi = 0; mi < 8; ++mi)
    #pragma unroll
    for (int ni = 0; ni < 2; ++ni)
      acc[mi][ni] = (f32x4){0.f, 0.f, 0.f, 0.f};

  mainloop256<2, 32, 2048>(aS, bS, &As[0][0], &Bs[0][0],
                           wid, wm, wn, l16, quad, sw, acc);

  // gather this tile's 256 row-sums (32 partials each), store reciprocal
  if (tid < 256) {
    const float4* pp = (const float4*)(part + ((long long)bz * 2048 + tile_m + tid) * 32);
    float s = 0.f;
    #pragma unroll
    for (int j = 0; j < 8; ++j) {
      const float4 f = pp[j];
      s += f.x + f.y + f.z + f.w;
    }
    rinv[tid] = 1.f / s;
  }
  __syncthreads();

  float* C = Cout + (long long)bz * 2048 * 1024;
  #pragma unroll
  for (int mi = 0; mi < 8; ++mi) {
    #pragma unroll
    for (int r = 0; r < 4; ++r) {
      const int rloc = wm + mi * 16 + quad * 4 + r;
      const float inv = rinv[rloc];
      const long long row = tile_m + rloc;
      #pragma unroll
      for (int ni = 0; ni < 2; ++ni) {
        const long long col = tile_n + wn + ni * 16 + l16;
        C[row * 1024 + col] = acc[mi][ni][r] * inv;
      }
    }
  }
}

// ---------------- all casts in one dispatch ----------------
__global__ __launch_bounds__(256)
void cast_all(const float* __restrict__ x,
              const float* __restrict__ Wq, const float* __restrict__ Wk,
              const float* __restrict__ Wv,
              __hip_bfloat16* __restrict__ xb, __hip_bfloat16* __restrict__ wcat)
{
  const int bx = blockIdx.x;
  const float* src;
  __hip_bfloat16* dst;
  int i;
  if (bx < 8192) {                      // x: 2097152 float4s
    src = x; dst = xb; i = bx * 256 + threadIdx.x;
  } else {                              // weights: 262144 float4s each
    const int which = (bx - 8192) >> 10;
    src = (which == 0) ? Wq : (which == 1) ? Wk : Wv;
    dst = wcat + (long long)which * 1048576;
    i = ((bx - 8192) & 1023) * 256 + threadIdx.x;
  }
  const float4 f = ((const float4*)src)[i];
  union { ushort4 u; __hip_bfloat16 h[4]; } r;
  r.h[0] = __float2bfloat16(f.x);
  r.h[1] = __float2bfloat16(f.y);
  r.h[2] = __float2bfloat16(f.z);
  r.h[3] = __float2bfloat16(f.w);
  ((ushort4*)dst)[i] = r.u;
}

extern "C" void kernel_launch(void* const* d_in, const int* in_sizes, int n_in,
                              void* d_out, int out_size, void* d_ws, size_t ws_size,
                              hipStream_t stream)
{
  (void)in_sizes; (void)n_in; (void)out_size; (void)ws_size;

  const float* x  = (const float*)d_in[0];
  const float* Wq = (const float*)d_in[1];
  const float* Wk = (const float*)d_in[2];
  const float* Wv = (const float*)d_in[3];
  float* out = (float*)d_out;

  char* ws = (char*)d_ws;
  __hip_bfloat16* xb   = (__hip_bfloat16*)(ws);            // dead after gemm_v
  float*          part = (float*)(ws);                     // reuses xb region (1 MB)
  __hip_bfloat16* wcat = (__hip_bfloat16*)(ws + (16LL << 20));
  __hip_bfloat16* Q    = (__hip_bfloat16*)(ws + (22LL << 20));
  __hip_bfloat16* Kk   = (__hip_bfloat16*)(ws + (38LL << 20));
  __hip_bfloat16* Vt   = (__hip_bfloat16*)(ws + (54LL << 20));
  __hip_bfloat16* S    = (__hip_bfloat16*)(ws + (70LL << 20));

  cast_all<<<11264, 256, 0, stream>>>(x, Wq, Wk, Wv, xb, wcat);

  // Q,K projection: 32x8 tiles of 256^2 = 256 blocks (1 clean round)
  gemm_qk<<<256, 512, 0, stream>>>(xb, wcat, Q, Kk);

  // V projection: 32x8 tiles of 256x128 = 256 blocks; V lands transposed
  gemm_v<<<256, 512, 0, stream>>>(xb, wcat + 2097152, Vt);

  // S = exp(Q K^T), row-sum partials -> part (overwrites dead xb)
  gemm_s_exp<<<dim3(8, 8, 4), 512, 0, stream>>>(Q, Kk, S, part);

  // O = (P Vt^T) / rowsum -> fp32 d_out
  gemm_pv<<<dim3(8, 8, 4), 512, 0, stream>>>(S, Vt, part, out);
}